// Round 11
// baseline (12047.375 us; speedup 1.0000x reference)
//
#include <hip/hip_runtime.h>
#include <cstdint>
#include <cstddef>

#define N_ 64
#define T_ 512
#define D_ 1024
#define H_ 1024
#define FH 4096  // 4*H

typedef __attribute__((ext_vector_type(8))) short bf16x8;
typedef __attribute__((ext_vector_type(4))) float f32x4;

static __device__ __forceinline__ uint16_t f2bf_(float f) {
  union { float f; uint32_t u; } v; v.f = f;
  uint32_t u = v.u + 0x7FFFu + ((v.u >> 16) & 1u);
  return (uint16_t)(u >> 16);
}
static __device__ __forceinline__ float bf2f_(uint16_t s) {
  union { uint32_t u; float f; } v; v.u = ((uint32_t)s) << 16;
  return v.f;
}
// split u64 of two packed (hi:lo) elements into hi-pair / lo-pair u32s
static __device__ __forceinline__ void unpk2_(unsigned long long e,
                                              uint32_t& hi, uint32_t& lo) {
  uint32_t a = (uint32_t)e, b = (uint32_t)(e >> 32);
  hi = (a >> 16) | (b & 0xFFFF0000u);
  lo = (a & 0xFFFFu) | (b << 16);
}

// plain cacheable u64 load (addresses are write-once -> no stale-line hazard)
#define ALD(p) (*(p))

// ---------------------------------------------------------------------------
// Pack W [1024][4096] into MFMA B-fragment order, split bf16 hi/lo (proven).
// ---------------------------------------------------------------------------
__global__ __launch_bounds__(256) void pack_w_k(const float* __restrict__ W,
                                                ushort* __restrict__ hi,
                                                ushort* __restrict__ lo) {
  const int i = blockIdx.x * 256 + threadIdx.x;  // 524288 = 256*32*64
  const int lane = i & 63, kc = (i >> 6) & 31, bid = i >> 11;
  const int c = lane & 15;
  const int col = (c >> 2) * H_ + (bid << 2) + (c & 3);
  const int k0 = (kc << 5) + ((lane >> 4) << 3);
  const size_t o = ((size_t)(bid * 32 + kc) * 64 + lane) * 8;
#pragma unroll
  for (int e = 0; e < 8; ++e) {
    float v = W[(size_t)(k0 + e) * FH + col];
    ushort h = f2bf_(v);
    hi[o + e] = h;
    lo[o + e] = f2bf_(v - bf2f_(h));
  }
}

// ---------------------------------------------------------------------------
// x: f32 -> bf16 hi/lo planes. Block 0 zeroes the 256 barrier flags.
// ---------------------------------------------------------------------------
__global__ __launch_bounds__(256) void split_f32_k(const float* __restrict__ src,
                                                   ushort* __restrict__ hi,
                                                   ushort* __restrict__ lo,
                                                   unsigned* bar) {
  if (bar != nullptr && blockIdx.x == 0) bar[threadIdx.x] = 0u;  // flags[256]
  const size_t i = (size_t)blockIdx.x * 256 + threadIdx.x;
  float4 v = reinterpret_cast<const float4*>(src)[i];
  ushort4 h, l;
  h.x = f2bf_(v.x); l.x = f2bf_(v.x - bf2f_(h.x));
  h.y = f2bf_(v.y); l.y = f2bf_(v.y - bf2f_(h.y));
  h.z = f2bf_(v.z); l.z = f2bf_(v.z - bf2f_(h.z));
  h.w = f2bf_(v.w); l.w = f2bf_(v.w - bf2f_(h.w));
  reinterpret_cast<ushort4*>(hi)[i] = h;
  reinterpret_cast<ushort4*>(lo)[i] = l;
}

// h0 f32 -> packed u32 (hi16:lo16). 64 blocks x 256 thr x 4 elems.
__global__ __launch_bounds__(256) void conv_h0pk_k(const float* __restrict__ src,
                                                   uint32_t* __restrict__ dst) {
  const int i = blockIdx.x * 256 + threadIdx.x;  // 16384 float4s
  float4 v = reinterpret_cast<const float4*>(src)[i];
  uint4 o;
  { ushort h = f2bf_(v.x); o.x = ((uint32_t)h << 16) | f2bf_(v.x - bf2f_(h)); }
  { ushort h = f2bf_(v.y); o.y = ((uint32_t)h << 16) | f2bf_(v.y - bf2f_(h)); }
  { ushort h = f2bf_(v.z); o.z = ((uint32_t)h << 16) | f2bf_(v.z - bf2f_(h)); }
  { ushort h = f2bf_(v.w); o.w = ((uint32_t)h << 16) | f2bf_(v.w - bf2f_(h)); }
  reinterpret_cast<uint4*>(dst)[i] = o;
}

// ---------------------------------------------------------------------------
// Persistent fused LSTM scan, round-10 skeleton + barrier/latency fixes:
// - RMW-free flag-array barrier: block stores t+1 to flags[bid] (write-through,
//   zero contention, monotonic); wave 0 polls all 256 flags via 2 bypassing
//   u64 loads/lane + __all ballot. No atomic-RMW serialization, no fences.
// - x-waves prefetch chunk 0 of x_{t+1} BETWEEN the barrier syncthreads: the
//   cold-HBM latency (~900cy) hides under the barrier wait.
// - vmcnt(0) drain only for h-waves (w<4) so x prefetch doesn't delay arrival.
//   Visibility chain: h stores -> per-wave vmcnt(0) -> syncthreads -> tid0
//   flag store (lands after) -> pollers observe -> read h (proven r9/r10).
// 256 blocks x 512 thr; block owns 4 h-cols. Waves: mt=w&3, kh=w>>2
// (0 -> h@Wh from LDS-B, 1 -> x_t@Wx). Split-bf16: D = Ah*Bh + Ah*Bl + Al*Bh.
// h state in unique-address ring hseq[0..T] (cacheable reads, r10-proven).
// ---------------------------------------------------------------------------
__global__ __launch_bounds__(512, 2) void lstm_persist_mfma(
    const ushort* __restrict__ Whh_g, const ushort* __restrict__ Whl_g,
    const ushort* __restrict__ Wxh, const ushort* __restrict__ Wxl,
    const ushort* __restrict__ xh, const ushort* __restrict__ xl,
    const float* __restrict__ bias,
    uint32_t* __restrict__ hseq,
    float* __restrict__ out, unsigned* __restrict__ bar) {
  extern __shared__ char ldsraw[];
  bf16x8* const WhH = (bf16x8*)ldsraw;       // 2048 units (32 KB)
  bf16x8* const WhL = WhH + 2048;            // 2048 units (32 KB)
  float* const pre = (float*)(WhL + 2048);   // 128*17 floats (8704 B)

  const int tid = threadIdx.x, bid = blockIdx.x;
  const int lane = tid & 63, w = tid >> 6;
  const int mt = w & 3, kh = w >> 2;
  const int arow = (mt << 4) | (lane & 15);
  const int kg = lane >> 4;
  const int dc = lane & 15, dr = (lane >> 4) << 2;
  const int en = tid >> 2, ejj = tid & 3;

  float bias4[4] = {0.f, 0.f, 0.f, 0.f};
  float creg = 0.f;
  if (tid < 256) {
#pragma unroll
    for (int g = 0; g < 4; ++g) bias4[g] = bias[g * H_ + (bid << 2) + ejj];
  }

  // one-time Wh stage into LDS (identity copy of packed layout)
  {
    const bf16x8* gh = reinterpret_cast<const bf16x8*>(Whh_g) + (size_t)bid * 2048;
    const bf16x8* gl = reinterpret_cast<const bf16x8*>(Whl_g) + (size_t)bid * 2048;
#pragma unroll
    for (int r = 0; r < 4; ++r) {
      int u = tid + (r << 9);
      WhH[u] = gh[u];
      WhL[u] = gl[u];
    }
  }
  __syncthreads();

  // Wx global fragment bases (x-wave)
  const bf16x8* Bxh = reinterpret_cast<const bf16x8*>(Wxh) + (size_t)bid * 2048 + lane;
  const bf16x8* Bxl = reinterpret_cast<const bf16x8*>(Wxl) + (size_t)bid * 2048 + lane;

  // ---- x-wave persistent pipeline state (prefetched chunk lives across the
  //      barrier; declared at function scope for cross-iteration liveness) ----
  const ushort* Axh = nullptr;
  const ushort* Axl = nullptr;
  bf16x8 pAH0, pAH1, pAH2, pAH3, pAL0, pAL1, pAL2, pAL3;
  bf16x8 pBH0, pBH1, pBH2, pBH3, pBL0, pBL1, pBL2, pBL3;
  bf16x8 qAH0, qAH1, qAH2, qAH3, qAL0, qAL1, qAL2, qAL3;
  bf16x8 qBH0, qBH1, qBH2, qBH3, qBL0, qBL1, qBL2, qBL3;

#define XLD(P, CH)                                                            \
  {                                                                           \
    const int kb = (CH) << 2;                                                 \
    P##AH0 = *reinterpret_cast<const bf16x8*>(Axh + ((kb + 0) << 5));         \
    P##AH1 = *reinterpret_cast<const bf16x8*>(Axh + ((kb + 1) << 5));         \
    P##AH2 = *reinterpret_cast<const bf16x8*>(Axh + ((kb + 2) << 5));         \
    P##AH3 = *reinterpret_cast<const bf16x8*>(Axh + ((kb + 3) << 5));         \
    P##AL0 = *reinterpret_cast<const bf16x8*>(Axl + ((kb + 0) << 5));         \
    P##AL1 = *reinterpret_cast<const bf16x8*>(Axl + ((kb + 1) << 5));         \
    P##AL2 = *reinterpret_cast<const bf16x8*>(Axl + ((kb + 2) << 5));         \
    P##AL3 = *reinterpret_cast<const bf16x8*>(Axl + ((kb + 3) << 5));         \
    P##BH0 = Bxh[(kb + 0) << 6];                                              \
    P##BH1 = Bxh[(kb + 1) << 6];                                              \
    P##BH2 = Bxh[(kb + 2) << 6];                                              \
    P##BH3 = Bxh[(kb + 3) << 6];                                              \
    P##BL0 = Bxl[(kb + 0) << 6];                                              \
    P##BL1 = Bxl[(kb + 1) << 6];                                              \
    P##BL2 = Bxl[(kb + 2) << 6];                                              \
    P##BL3 = Bxl[(kb + 3) << 6];                                              \
  }

#define XCOMP(P)                                                              \
  {                                                                           \
    acc0 = __builtin_amdgcn_mfma_f32_16x16x32_bf16(P##AH0, P##BH0, acc0, 0, 0, 0); \
    acc1 = __builtin_amdgcn_mfma_f32_16x16x32_bf16(P##AH1, P##BH1, acc1, 0, 0, 0); \
    acc0 = __builtin_amdgcn_mfma_f32_16x16x32_bf16(P##AH0, P##BL0, acc0, 0, 0, 0); \
    acc1 = __builtin_amdgcn_mfma_f32_16x16x32_bf16(P##AH1, P##BL1, acc1, 0, 0, 0); \
    acc0 = __builtin_amdgcn_mfma_f32_16x16x32_bf16(P##AL0, P##BH0, acc0, 0, 0, 0); \
    acc1 = __builtin_amdgcn_mfma_f32_16x16x32_bf16(P##AL1, P##BH1, acc1, 0, 0, 0); \
    acc0 = __builtin_amdgcn_mfma_f32_16x16x32_bf16(P##AH2, P##BH2, acc0, 0, 0, 0); \
    acc1 = __builtin_amdgcn_mfma_f32_16x16x32_bf16(P##AH3, P##BH3, acc1, 0, 0, 0); \
    acc0 = __builtin_amdgcn_mfma_f32_16x16x32_bf16(P##AH2, P##BL2, acc0, 0, 0, 0); \
    acc1 = __builtin_amdgcn_mfma_f32_16x16x32_bf16(P##AH3, P##BL3, acc1, 0, 0, 0); \
    acc0 = __builtin_amdgcn_mfma_f32_16x16x32_bf16(P##AL2, P##BH2, acc0, 0, 0, 0); \
    acc1 = __builtin_amdgcn_mfma_f32_16x16x32_bf16(P##AL3, P##BH3, acc1, 0, 0, 0); \
  }

  if (kh == 1) {  // prologue prefetch: chunk 0 of t=0
    Axh = xh + ((size_t)arow * T_) * D_ + (kg << 3);
    Axl = xl + ((size_t)arow * T_) * D_ + (kg << 3);
    XLD(p, 0)
  }

  for (int t = 0; t < T_; ++t) {
    f32x4 acc0 = {0.f, 0.f, 0.f, 0.f};
    f32x4 acc1 = {0.f, 0.f, 0.f, 0.f};

    if (kh == 0) {
      // ---- h @ Wh : A via cacheable u64 loads of hseq[t], B from LDS ----
      const unsigned long long* Apk =
          (const unsigned long long*)(hseq + (size_t)t * 65536) +
          arow * 512 + kg * 4;

      unsigned long long pa0, pa1, pa2, pa3, pb0, pb1, pb2, pb3;
      unsigned long long pc0, pc1, pc2, pc3, pd0, pd1, pd2, pd3;
      unsigned long long qa0, qa1, qa2, qa3, qb0, qb1, qb2, qb3;
      unsigned long long qc0, qc1, qc2, qc3, qd0, qd1, qd2, qd3;

#define HLD(P, CH)                                                            \
  {                                                                           \
    const unsigned long long* ap_ = Apk + ((CH) << 6);                        \
    P##a0 = ALD(ap_ + 0);  P##a1 = ALD(ap_ + 1);                              \
    P##a2 = ALD(ap_ + 2);  P##a3 = ALD(ap_ + 3);                              \
    P##b0 = ALD(ap_ + 16); P##b1 = ALD(ap_ + 17);                             \
    P##b2 = ALD(ap_ + 18); P##b3 = ALD(ap_ + 19);                             \
    P##c0 = ALD(ap_ + 32); P##c1 = ALD(ap_ + 33);                             \
    P##c2 = ALD(ap_ + 34); P##c3 = ALD(ap_ + 35);                             \
    P##d0 = ALD(ap_ + 48); P##d1 = ALD(ap_ + 49);                             \
    P##d2 = ALD(ap_ + 50); P##d3 = ALD(ap_ + 51);                             \
  }

#define HKC(E0, E1, E2, E3, KCG, ACC)                                         \
  {                                                                           \
    union { uint32_t u[4]; bf16x8 v; } fh_, fl_;                              \
    unpk2_(E0, fh_.u[0], fl_.u[0]);                                           \
    unpk2_(E1, fh_.u[1], fl_.u[1]);                                           \
    unpk2_(E2, fh_.u[2], fl_.u[2]);                                           \
    unpk2_(E3, fh_.u[3], fl_.u[3]);                                           \
    bf16x8 bh_ = WhH[((KCG) << 6) + lane];                                    \
    bf16x8 bl_ = WhL[((KCG) << 6) + lane];                                    \
    ACC = __builtin_amdgcn_mfma_f32_16x16x32_bf16(fh_.v, bh_, ACC, 0, 0, 0);  \
    ACC = __builtin_amdgcn_mfma_f32_16x16x32_bf16(fh_.v, bl_, ACC, 0, 0, 0);  \
    ACC = __builtin_amdgcn_mfma_f32_16x16x32_bf16(fl_.v, bh_, ACC, 0, 0, 0);  \
  }

#define HCOMP(P, CH)                                                          \
  HKC(P##a0, P##a1, P##a2, P##a3, (CH) * 4 + 0, acc0)                         \
  HKC(P##b0, P##b1, P##b2, P##b3, (CH) * 4 + 1, acc1)                         \
  HKC(P##c0, P##c1, P##c2, P##c3, (CH) * 4 + 2, acc0)                         \
  HKC(P##d0, P##d1, P##d2, P##d3, (CH) * 4 + 3, acc1)

      HLD(p, 0)
      HLD(q, 1) HCOMP(p, 0)
      HLD(p, 2) HCOMP(q, 1)
      HLD(q, 3) HCOMP(p, 2)
      HLD(p, 4) HCOMP(q, 3)
      HLD(q, 5) HCOMP(p, 4)
      HLD(p, 6) HCOMP(q, 5)
      HLD(q, 7) HCOMP(p, 6)
      HCOMP(q, 7)
#undef HLD
#undef HKC
#undef HCOMP
    } else {
      // ---- x_t @ Wx : chunk 0 already prefetched (pre-barrier) ----
      XLD(q, 1) XCOMP(p)
      XLD(p, 2) XCOMP(q)
      XLD(q, 3) XCOMP(p)
      XLD(p, 4) XCOMP(q)
      XLD(q, 5) XCOMP(p)
      XLD(p, 6) XCOMP(q)
      XLD(q, 7) XCOMP(p)
      XCOMP(q)
    }

    f32x4 accs = acc0 + acc1;

    // D layout (m89-verified): col = lane&15, row = (lane>>4)*4 + r
#pragma unroll
    for (int r = 0; r < 4; ++r)
      pre[((kh << 6) + (mt << 4) + dr + r) * 17 + dc] = accs[r];
    __syncthreads();

    if (tid < 256) {
      float a[4];
#pragma unroll
      for (int g = 0; g < 4; ++g)
        a[g] = pre[en * 17 + (g << 2) + ejj] +
               pre[(64 + en) * 17 + (g << 2) + ejj] + bias4[g];
      float iv = 1.f / (1.f + __expf(-a[0]));
      float fv = 1.f / (1.f + __expf(-a[1]));
      float ov = 1.f / (1.f + __expf(-a[2]));
      float gv = tanhf(a[3]);
      creg = fmaf(fv, creg, iv * gv);
      float hn = ov * tanhf(creg);
      out[(size_t)en * ((size_t)T_ * H_) + (size_t)t * H_ + (bid << 2) + ejj] = hn;
      ushort hh = f2bf_(hn);
      uint32_t pk = ((uint32_t)hh << 16) | f2bf_(hn - bf2f_(hh));
      __hip_atomic_store(&hseq[(size_t)(t + 1) * 65536 + en * H_ + (bid << 2) + ejj],
                         pk, __ATOMIC_RELAXED, __HIP_MEMORY_SCOPE_AGENT);
    }

    // ---- drain h stores (h-waves only; x prefetch must not delay arrival) --
    if (w < 4) asm volatile("s_waitcnt vmcnt(0)" ::: "memory");
    __syncthreads();

    // x-waves: prefetch chunk 0 of x_{t+1} (flies under the barrier wait)
    if (kh == 1) {
      const int tn = (t + 1 < T_) ? (t + 1) : t;
      Axh = xh + ((size_t)arow * T_ + tn) * D_ + (kg << 3);
      Axl = xl + ((size_t)arow * T_ + tn) * D_ + (kg << 3);
      XLD(p, 0)
    }

    // wave 0: arrive (own-slot store, no RMW) + poll all 256 flags
    if (tid < 64) {
      if (tid == 0)
        __hip_atomic_store(&bar[bid], (unsigned)(t + 1), __ATOMIC_RELAXED,
                           __HIP_MEMORY_SCOPE_AGENT);
      const unsigned long long* fl = (const unsigned long long*)bar;
      const unsigned tgt = (unsigned)(t + 1);
      for (;;) {
        unsigned long long v0 = __hip_atomic_load(fl + tid, __ATOMIC_RELAXED,
                                                  __HIP_MEMORY_SCOPE_AGENT);
        unsigned long long v1 = __hip_atomic_load(fl + 64 + tid, __ATOMIC_RELAXED,
                                                  __HIP_MEMORY_SCOPE_AGENT);
        bool ok = ((unsigned)v0 >= tgt) && ((unsigned)(v0 >> 32) >= tgt) &&
                  ((unsigned)v1 >= tgt) && ((unsigned)(v1 >> 32) >= tgt);
        if (__all((int)ok)) break;
      }
    }
    __syncthreads();
  }
#undef XLD
#undef XCOMP
}

// ---------------------------------------------------------------------------
// Fallback (tiny ws): fused per-step VALU kernel (round-1 proven). Slow.
// ---------------------------------------------------------------------------
__global__ __launch_bounds__(256) void lstm_step_fb(
    const float* __restrict__ xt, const float* __restrict__ Wx,
    const float* __restrict__ Wh, const float* __restrict__ bias,
    const float* __restrict__ h_prev, long long hstride,
    float* __restrict__ cbuf, float* __restrict__ h_out, int first) {
  __shared__ float hS[32][128];
  __shared__ float wT[32][132];
  __shared__ float pre[32][34];
  const int tid = threadIdx.x;
  const int colblk = blockIdx.x & 127;
  const int nh = blockIdx.x >> 7;
  const int j0 = colblk << 3;
  const int n0 = nh << 5;
  const int ng = tid >> 4, cg2 = tid & 15;
  const int na = ng << 1, ca = cg2 << 1;

  float acc[2][2] = {{0.f, 0.f}, {0.f, 0.f}};

#pragma unroll
  for (int pr = 0; pr < 2; ++pr) {
    const float* src = (pr == 0) ? h_prev : xt;
    long long sstr = (pr == 0) ? hstride : (long long)T_ * D_;
    const float* W = (pr == 0) ? Wh : Wx;
    for (int k0 = 0; k0 < 1024; k0 += 128) {
      __syncthreads();
#pragma unroll
      for (int p = 0; p < 4; ++p) {
        int idx = tid + (p << 8);
        int r = idx >> 5, c4 = (idx & 31) << 2;
        *reinterpret_cast<float4*>(&hS[r][c4]) =
            *reinterpret_cast<const float4*>(src + (size_t)(n0 + r) * sstr + k0 + c4);
      }
#pragma unroll
      for (int p = 0; p < 4; ++p) {
        int idx = tid + (p << 8);
        int k = idx >> 3, sub = idx & 7;
        int g = sub >> 1, hf = (sub & 1) << 2;
        float4 v = *reinterpret_cast<const float4*>(
            W + (size_t)(k0 + k) * FH + g * H_ + j0 + hf);
        int cb = (g << 3) + hf;
        wT[cb][k] = v.x; wT[cb + 1][k] = v.y; wT[cb + 2][k] = v.z; wT[cb + 3][k] = v.w;
      }
      __syncthreads();
#pragma unroll
      for (int kk = 0; kk < 128; kk += 4) {
        float4 h0v = *reinterpret_cast<const float4*>(&hS[na][kk]);
        float4 h1v = *reinterpret_cast<const float4*>(&hS[na + 1][kk]);
        float4 w0 = *reinterpret_cast<const float4*>(&wT[ca][kk]);
        float4 w1 = *reinterpret_cast<const float4*>(&wT[ca + 1][kk]);
        acc[0][0] = fmaf(h0v.x, w0.x, acc[0][0]); acc[0][0] = fmaf(h0v.y, w0.y, acc[0][0]);
        acc[0][0] = fmaf(h0v.z, w0.z, acc[0][0]); acc[0][0] = fmaf(h0v.w, w0.w, acc[0][0]);
        acc[0][1] = fmaf(h0v.x, w1.x, acc[0][1]); acc[0][1] = fmaf(h0v.y, w1.y, acc[0][1]);
        acc[0][1] = fmaf(h0v.z, w1.z, acc[0][1]); acc[0][1] = fmaf(h0v.w, w1.w, acc[0][1]);
        acc[1][0] = fmaf(h1v.x, w0.x, acc[1][0]); acc[1][0] = fmaf(h1v.y, w0.y, acc[1][0]);
        acc[1][0] = fmaf(h1v.z, w0.z, acc[1][0]); acc[1][0] = fmaf(h1v.w, w0.w, acc[1][0]);
        acc[1][1] = fmaf(h1v.x, w1.x, acc[1][1]); acc[1][1] = fmaf(h1v.y, w1.y, acc[1][1]);
        acc[1][1] = fmaf(h1v.z, w1.z, acc[1][1]); acc[1][1] = fmaf(h1v.w, w1.w, acc[1][1]);
      }
    }
  }

  pre[na][ca] = acc[0][0];
  pre[na][ca + 1] = acc[0][1];
  pre[na + 1][ca] = acc[1][0];
  pre[na + 1][ca + 1] = acc[1][1];
  __syncthreads();

  const int nl = tid >> 3, jl = tid & 7;
  const int n = n0 + nl;
  const int jg = j0 + jl;
  float ai = pre[nl][jl] + bias[jg];
  float af = pre[nl][8 + jl] + bias[H_ + jg];
  float ao = pre[nl][16 + jl] + bias[2 * H_ + jg];
  float ag = pre[nl][24 + jl] + bias[3 * H_ + jg];
  float cp = first ? 0.0f : cbuf[n * H_ + jg];
  float iv = 1.f / (1.f + __expf(-ai));
  float fv = 1.f / (1.f + __expf(-af));
  float ov = 1.f / (1.f + __expf(-ao));
  float gv = tanhf(ag);
  float cn = fmaf(fv, cp, iv * gv);
  cbuf[n * H_ + jg] = cn;
  h_out[(size_t)n * ((size_t)T_ * H_) + jg] = ov * tanhf(cn);
}

// ---------------------------------------------------------------------------
extern "C" void kernel_launch(void* const* d_in, const int* in_sizes, int n_in,
                              void* d_out, int out_size, void* d_ws, size_t ws_size,
                              hipStream_t stream) {
  (void)in_sizes; (void)n_in; (void)out_size;
  const float* x  = (const float*)d_in[0];
  const float* h0 = (const float*)d_in[1];
  const float* Wx = (const float*)d_in[2];
  const float* Wh = (const float*)d_in[3];
  const float* b  = (const float*)d_in[4];
  float* out = (float*)d_out;

  const size_t MB = 1u << 20;
  char* p = (char*)d_ws;

  if (ws_size >= 300 * MB) {
    unsigned* bar = (unsigned*)p;               // flags[256]
    ushort* Whh = (ushort*)(p + 1 * MB);
    ushort* Whl = (ushort*)(p + 9 * MB);
    ushort* Wxh = (ushort*)(p + 17 * MB);
    ushort* Wxl = (ushort*)(p + 25 * MB);
    uint32_t* hseq = (uint32_t*)(p + 33 * MB);  // 513 * 256 KB = 128.25 MB
    ushort* xh = (ushort*)(p + 168 * MB);       // 64 MB
    ushort* xl = (ushort*)(p + 232 * MB);       // 64 MB (ends at 296 MB)

    pack_w_k<<<dim3(2048), dim3(256), 0, stream>>>(Wh, Whh, Whl);
    pack_w_k<<<dim3(2048), dim3(256), 0, stream>>>(Wx, Wxh, Wxl);
    // x: 8,388,608 float4 -> 32768 blocks (zeroes barrier flags)
    split_f32_k<<<dim3(32768), dim3(256), 0, stream>>>(x, xh, xl, bar);
    // h0 -> packed u32 into hseq[0]
    conv_h0pk_k<<<dim3(64), dim3(256), 0, stream>>>(h0, hseq);

    const unsigned SH = 2048 * 16 * 2 + 128 * 17 * 4;  // 74240 B
    hipFuncSetAttribute((const void*)lstm_persist_mfma,
                        hipFuncAttributeMaxDynamicSharedMemorySize, (int)SH);
    lstm_persist_mfma<<<dim3(256), dim3(512), SH, stream>>>(
        Whh, Whl, Wxh, Wxl, xh, xl, b, hseq, out, bar);
  } else {
    float* cbuf = (float*)p;  // 256 KB
    for (int t = 0; t < T_; ++t) {
      const float* hp = (t == 0) ? h0 : out + (size_t)(t - 1) * H_;
      long long hstr = (t == 0) ? (long long)H_ : (long long)T_ * H_;
      lstm_step_fb<<<dim3(256), dim3(256), 0, stream>>>(
          x + (size_t)t * D_, Wx, Wh, b, hp, hstr, cbuf,
          out + (size_t)t * H_, t == 0);
    }
  }
}

// Round 12
// 10790.190 us; speedup vs baseline: 1.1165x; 1.1165x over previous
//
#include <hip/hip_runtime.h>
#include <cstdint>
#include <cstddef>

#define N_ 64
#define T_ 512
#define D_ 1024
#define H_ 1024
#define FH 4096  // 4*H

typedef __attribute__((ext_vector_type(8))) short bf16x8;
typedef __attribute__((ext_vector_type(4))) float f32x4;

static __device__ __forceinline__ uint16_t f2bf_(float f) {
  union { float f; uint32_t u; } v; v.f = f;
  uint32_t u = v.u + 0x7FFFu + ((v.u >> 16) & 1u);
  return (uint16_t)(u >> 16);
}
static __device__ __forceinline__ float bf2f_(uint16_t s) {
  union { uint32_t u; float f; } v; v.u = ((uint32_t)s) << 16;
  return v.f;
}
// split u64 of two packed (hi:lo) elements into hi-pair / lo-pair u32s
static __device__ __forceinline__ void unpk2_(unsigned long long e,
                                              uint32_t& hi, uint32_t& lo) {
  uint32_t a = (uint32_t)e, b = (uint32_t)(e >> 32);
  hi = (a >> 16) | (b & 0xFFFF0000u);
  lo = (a & 0xFFFFu) | (b << 16);
}

// plain cacheable u64 load (addresses are write-once -> no stale-line hazard)
#define ALD(p) (*(p))

// ---------------------------------------------------------------------------
// Pack W [1024][4096] into MFMA B-fragment order, split bf16 hi/lo (proven).
// ---------------------------------------------------------------------------
__global__ __launch_bounds__(256) void pack_w_k(const float* __restrict__ W,
                                                ushort* __restrict__ hi,
                                                ushort* __restrict__ lo) {
  const int i = blockIdx.x * 256 + threadIdx.x;  // 524288 = 256*32*64
  const int lane = i & 63, kc = (i >> 6) & 31, bid = i >> 11;
  const int c = lane & 15;
  const int col = (c >> 2) * H_ + (bid << 2) + (c & 3);
  const int k0 = (kc << 5) + ((lane >> 4) << 3);
  const size_t o = ((size_t)(bid * 32 + kc) * 64 + lane) * 8;
#pragma unroll
  for (int e = 0; e < 8; ++e) {
    float v = W[(size_t)(k0 + e) * FH + col];
    ushort h = f2bf_(v);
    hi[o + e] = h;
    lo[o + e] = f2bf_(v - bf2f_(h));
  }
}

// ---------------------------------------------------------------------------
// x: f32 -> bf16 hi/lo planes. Block 0 zeroes the 512 barrier words
// (flags[256] + release word region).
// ---------------------------------------------------------------------------
__global__ __launch_bounds__(256) void split_f32_k(const float* __restrict__ src,
                                                   ushort* __restrict__ hi,
                                                   ushort* __restrict__ lo,
                                                   unsigned* bar) {
  if (bar != nullptr && blockIdx.x == 0) {
    bar[threadIdx.x] = 0u;
    bar[256 + threadIdx.x] = 0u;
  }
  const size_t i = (size_t)blockIdx.x * 256 + threadIdx.x;
  float4 v = reinterpret_cast<const float4*>(src)[i];
  ushort4 h, l;
  h.x = f2bf_(v.x); l.x = f2bf_(v.x - bf2f_(h.x));
  h.y = f2bf_(v.y); l.y = f2bf_(v.y - bf2f_(h.y));
  h.z = f2bf_(v.z); l.z = f2bf_(v.z - bf2f_(h.z));
  h.w = f2bf_(v.w); l.w = f2bf_(v.w - bf2f_(h.w));
  reinterpret_cast<ushort4*>(hi)[i] = h;
  reinterpret_cast<ushort4*>(lo)[i] = l;
}

// h0 f32 -> packed u32 (hi16:lo16). 64 blocks x 256 thr x 4 elems.
__global__ __launch_bounds__(256) void conv_h0pk_k(const float* __restrict__ src,
                                                   uint32_t* __restrict__ dst) {
  const int i = blockIdx.x * 256 + threadIdx.x;  // 16384 float4s
  float4 v = reinterpret_cast<const float4*>(src)[i];
  uint4 o;
  { ushort h = f2bf_(v.x); o.x = ((uint32_t)h << 16) | f2bf_(v.x - bf2f_(h)); }
  { ushort h = f2bf_(v.y); o.y = ((uint32_t)h << 16) | f2bf_(v.y - bf2f_(h)); }
  { ushort h = f2bf_(v.z); o.z = ((uint32_t)h << 16) | f2bf_(v.z - bf2f_(h)); }
  { ushort h = f2bf_(v.w); o.w = ((uint32_t)h << 16) | f2bf_(v.w - bf2f_(h)); }
  reinterpret_cast<uint4*>(dst)[i] = o;
}

// ---------------------------------------------------------------------------
// Persistent fused LSTM scan, round-11 skeleton + single-aggregator barrier:
// - Arrival: per-block own-slot flag store (RMW-free, zero contention).
// - ONLY block 0 polls all 256 flags (64 lanes x 2 u64 = 1 KB/iter from one
//   block — r11's mistake was 256 blocks x 64 lanes polling = fabric flood,
//   FETCH 1.08->4.99 GB). On completion block 0 stores ONE release word.
// - All blocks poll the single release word (1 u32, s_sleep backoff).
// - x-waves prefetch chunk 0 of x_{t+1} between the barrier syncthreads.
// - vmcnt(0) drain only for h-waves (w<4). Visibility chain proven r9-r11.
// 256 blocks x 512 thr; block owns 4 h-cols. Waves: mt=w&3, kh=w>>2
// (0 -> h@Wh from LDS-B, 1 -> x_t@Wx). Split-bf16: D = Ah*Bh + Ah*Bl + Al*Bh.
// h state in unique-address ring hseq[0..T] (cacheable reads, r10-proven).
// ---------------------------------------------------------------------------
__global__ __launch_bounds__(512, 2) void lstm_persist_mfma(
    const ushort* __restrict__ Whh_g, const ushort* __restrict__ Whl_g,
    const ushort* __restrict__ Wxh, const ushort* __restrict__ Wxl,
    const ushort* __restrict__ xh, const ushort* __restrict__ xl,
    const float* __restrict__ bias,
    uint32_t* __restrict__ hseq,
    float* __restrict__ out, unsigned* __restrict__ bar) {
  extern __shared__ char ldsraw[];
  bf16x8* const WhH = (bf16x8*)ldsraw;       // 2048 units (32 KB)
  bf16x8* const WhL = WhH + 2048;            // 2048 units (32 KB)
  float* const pre = (float*)(WhL + 2048);   // 128*17 floats (8704 B)

  const int tid = threadIdx.x, bid = blockIdx.x;
  const int lane = tid & 63, w = tid >> 6;
  const int mt = w & 3, kh = w >> 2;
  const int arow = (mt << 4) | (lane & 15);
  const int kg = lane >> 4;
  const int dc = lane & 15, dr = (lane >> 4) << 2;
  const int en = tid >> 2, ejj = tid & 3;

  unsigned* const rel = bar + 384;  // release word, own 128-B region

  float bias4[4] = {0.f, 0.f, 0.f, 0.f};
  float creg = 0.f;
  if (tid < 256) {
#pragma unroll
    for (int g = 0; g < 4; ++g) bias4[g] = bias[g * H_ + (bid << 2) + ejj];
  }

  // one-time Wh stage into LDS (identity copy of packed layout)
  {
    const bf16x8* gh = reinterpret_cast<const bf16x8*>(Whh_g) + (size_t)bid * 2048;
    const bf16x8* gl = reinterpret_cast<const bf16x8*>(Whl_g) + (size_t)bid * 2048;
#pragma unroll
    for (int r = 0; r < 4; ++r) {
      int u = tid + (r << 9);
      WhH[u] = gh[u];
      WhL[u] = gl[u];
    }
  }
  __syncthreads();

  // Wx global fragment bases (x-wave)
  const bf16x8* Bxh = reinterpret_cast<const bf16x8*>(Wxh) + (size_t)bid * 2048 + lane;
  const bf16x8* Bxl = reinterpret_cast<const bf16x8*>(Wxl) + (size_t)bid * 2048 + lane;

  // ---- x-wave persistent pipeline state (prefetched chunk lives across the
  //      barrier; declared at function scope for cross-iteration liveness) ----
  const ushort* Axh = nullptr;
  const ushort* Axl = nullptr;
  bf16x8 pAH0, pAH1, pAH2, pAH3, pAL0, pAL1, pAL2, pAL3;
  bf16x8 pBH0, pBH1, pBH2, pBH3, pBL0, pBL1, pBL2, pBL3;
  bf16x8 qAH0, qAH1, qAH2, qAH3, qAL0, qAL1, qAL2, qAL3;
  bf16x8 qBH0, qBH1, qBH2, qBH3, qBL0, qBL1, qBL2, qBL3;

#define XLD(P, CH)                                                            \
  {                                                                           \
    const int kb = (CH) << 2;                                                 \
    P##AH0 = *reinterpret_cast<const bf16x8*>(Axh + ((kb + 0) << 5));         \
    P##AH1 = *reinterpret_cast<const bf16x8*>(Axh + ((kb + 1) << 5));         \
    P##AH2 = *reinterpret_cast<const bf16x8*>(Axh + ((kb + 2) << 5));         \
    P##AH3 = *reinterpret_cast<const bf16x8*>(Axh + ((kb + 3) << 5));         \
    P##AL0 = *reinterpret_cast<const bf16x8*>(Axl + ((kb + 0) << 5));         \
    P##AL1 = *reinterpret_cast<const bf16x8*>(Axl + ((kb + 1) << 5));         \
    P##AL2 = *reinterpret_cast<const bf16x8*>(Axl + ((kb + 2) << 5));         \
    P##AL3 = *reinterpret_cast<const bf16x8*>(Axl + ((kb + 3) << 5));         \
    P##BH0 = Bxh[(kb + 0) << 6];                                              \
    P##BH1 = Bxh[(kb + 1) << 6];                                              \
    P##BH2 = Bxh[(kb + 2) << 6];                                              \
    P##BH3 = Bxh[(kb + 3) << 6];                                              \
    P##BL0 = Bxl[(kb + 0) << 6];                                              \
    P##BL1 = Bxl[(kb + 1) << 6];                                              \
    P##BL2 = Bxl[(kb + 2) << 6];                                              \
    P##BL3 = Bxl[(kb + 3) << 6];                                              \
  }

#define XCOMP(P)                                                              \
  {                                                                           \
    acc0 = __builtin_amdgcn_mfma_f32_16x16x32_bf16(P##AH0, P##BH0, acc0, 0, 0, 0); \
    acc1 = __builtin_amdgcn_mfma_f32_16x16x32_bf16(P##AH1, P##BH1, acc1, 0, 0, 0); \
    acc0 = __builtin_amdgcn_mfma_f32_16x16x32_bf16(P##AH0, P##BL0, acc0, 0, 0, 0); \
    acc1 = __builtin_amdgcn_mfma_f32_16x16x32_bf16(P##AH1, P##BL1, acc1, 0, 0, 0); \
    acc0 = __builtin_amdgcn_mfma_f32_16x16x32_bf16(P##AL0, P##BH0, acc0, 0, 0, 0); \
    acc1 = __builtin_amdgcn_mfma_f32_16x16x32_bf16(P##AL1, P##BH1, acc1, 0, 0, 0); \
    acc0 = __builtin_amdgcn_mfma_f32_16x16x32_bf16(P##AH2, P##BH2, acc0, 0, 0, 0); \
    acc1 = __builtin_amdgcn_mfma_f32_16x16x32_bf16(P##AH3, P##BH3, acc1, 0, 0, 0); \
    acc0 = __builtin_amdgcn_mfma_f32_16x16x32_bf16(P##AH2, P##BL2, acc0, 0, 0, 0); \
    acc1 = __builtin_amdgcn_mfma_f32_16x16x32_bf16(P##AH3, P##BL3, acc1, 0, 0, 0); \
    acc0 = __builtin_amdgcn_mfma_f32_16x16x32_bf16(P##AL2, P##BH2, acc0, 0, 0, 0); \
    acc1 = __builtin_amdgcn_mfma_f32_16x16x32_bf16(P##AL3, P##BH3, acc1, 0, 0, 0); \
  }

  if (kh == 1) {  // prologue prefetch: chunk 0 of t=0
    Axh = xh + ((size_t)arow * T_) * D_ + (kg << 3);
    Axl = xl + ((size_t)arow * T_) * D_ + (kg << 3);
    XLD(p, 0)
  }

  for (int t = 0; t < T_; ++t) {
    f32x4 acc0 = {0.f, 0.f, 0.f, 0.f};
    f32x4 acc1 = {0.f, 0.f, 0.f, 0.f};

    if (kh == 0) {
      // ---- h @ Wh : A via cacheable u64 loads of hseq[t], B from LDS ----
      const unsigned long long* Apk =
          (const unsigned long long*)(hseq + (size_t)t * 65536) +
          arow * 512 + kg * 4;

      unsigned long long pa0, pa1, pa2, pa3, pb0, pb1, pb2, pb3;
      unsigned long long pc0, pc1, pc2, pc3, pd0, pd1, pd2, pd3;
      unsigned long long qa0, qa1, qa2, qa3, qb0, qb1, qb2, qb3;
      unsigned long long qc0, qc1, qc2, qc3, qd0, qd1, qd2, qd3;

#define HLD(P, CH)                                                            \
  {                                                                           \
    const unsigned long long* ap_ = Apk + ((CH) << 6);                        \
    P##a0 = ALD(ap_ + 0);  P##a1 = ALD(ap_ + 1);                              \
    P##a2 = ALD(ap_ + 2);  P##a3 = ALD(ap_ + 3);                              \
    P##b0 = ALD(ap_ + 16); P##b1 = ALD(ap_ + 17);                             \
    P##b2 = ALD(ap_ + 18); P##b3 = ALD(ap_ + 19);                             \
    P##c0 = ALD(ap_ + 32); P##c1 = ALD(ap_ + 33);                             \
    P##c2 = ALD(ap_ + 34); P##c3 = ALD(ap_ + 35);                             \
    P##d0 = ALD(ap_ + 48); P##d1 = ALD(ap_ + 49);                             \
    P##d2 = ALD(ap_ + 50); P##d3 = ALD(ap_ + 51);                             \
  }

#define HKC(E0, E1, E2, E3, KCG, ACC)                                         \
  {                                                                           \
    union { uint32_t u[4]; bf16x8 v; } fh_, fl_;                              \
    unpk2_(E0, fh_.u[0], fl_.u[0]);                                           \
    unpk2_(E1, fh_.u[1], fl_.u[1]);                                           \
    unpk2_(E2, fh_.u[2], fl_.u[2]);                                           \
    unpk2_(E3, fh_.u[3], fl_.u[3]);                                           \
    bf16x8 bh_ = WhH[((KCG) << 6) + lane];                                    \
    bf16x8 bl_ = WhL[((KCG) << 6) + lane];                                    \
    ACC = __builtin_amdgcn_mfma_f32_16x16x32_bf16(fh_.v, bh_, ACC, 0, 0, 0);  \
    ACC = __builtin_amdgcn_mfma_f32_16x16x32_bf16(fh_.v, bl_, ACC, 0, 0, 0);  \
    ACC = __builtin_amdgcn_mfma_f32_16x16x32_bf16(fl_.v, bh_, ACC, 0, 0, 0);  \
  }

#define HCOMP(P, CH)                                                          \
  HKC(P##a0, P##a1, P##a2, P##a3, (CH) * 4 + 0, acc0)                         \
  HKC(P##b0, P##b1, P##b2, P##b3, (CH) * 4 + 1, acc1)                         \
  HKC(P##c0, P##c1, P##c2, P##c3, (CH) * 4 + 2, acc0)                         \
  HKC(P##d0, P##d1, P##d2, P##d3, (CH) * 4 + 3, acc1)

      HLD(p, 0)
      HLD(q, 1) HCOMP(p, 0)
      HLD(p, 2) HCOMP(q, 1)
      HLD(q, 3) HCOMP(p, 2)
      HLD(p, 4) HCOMP(q, 3)
      HLD(q, 5) HCOMP(p, 4)
      HLD(p, 6) HCOMP(q, 5)
      HLD(q, 7) HCOMP(p, 6)
      HCOMP(q, 7)
#undef HLD
#undef HKC
#undef HCOMP
    } else {
      // ---- x_t @ Wx : chunk 0 already prefetched (pre-barrier) ----
      XLD(q, 1) XCOMP(p)
      XLD(p, 2) XCOMP(q)
      XLD(q, 3) XCOMP(p)
      XLD(p, 4) XCOMP(q)
      XLD(q, 5) XCOMP(p)
      XLD(p, 6) XCOMP(q)
      XLD(q, 7) XCOMP(p)
      XCOMP(q)
    }

    f32x4 accs = acc0 + acc1;

    // D layout (m89-verified): col = lane&15, row = (lane>>4)*4 + r
#pragma unroll
    for (int r = 0; r < 4; ++r)
      pre[((kh << 6) + (mt << 4) + dr + r) * 17 + dc] = accs[r];
    __syncthreads();

    if (tid < 256) {
      float a[4];
#pragma unroll
      for (int g = 0; g < 4; ++g)
        a[g] = pre[en * 17 + (g << 2) + ejj] +
               pre[(64 + en) * 17 + (g << 2) + ejj] + bias4[g];
      float iv = 1.f / (1.f + __expf(-a[0]));
      float fv = 1.f / (1.f + __expf(-a[1]));
      float ov = 1.f / (1.f + __expf(-a[2]));
      float gv = tanhf(a[3]);
      creg = fmaf(fv, creg, iv * gv);
      float hn = ov * tanhf(creg);
      out[(size_t)en * ((size_t)T_ * H_) + (size_t)t * H_ + (bid << 2) + ejj] = hn;
      ushort hh = f2bf_(hn);
      uint32_t pk = ((uint32_t)hh << 16) | f2bf_(hn - bf2f_(hh));
      __hip_atomic_store(&hseq[(size_t)(t + 1) * 65536 + en * H_ + (bid << 2) + ejj],
                         pk, __ATOMIC_RELAXED, __HIP_MEMORY_SCOPE_AGENT);
    }

    // ---- drain h stores (h-waves only; x prefetch must not delay arrival) --
    if (w < 4) asm volatile("s_waitcnt vmcnt(0)" ::: "memory");
    __syncthreads();

    // x-waves: prefetch chunk 0 of x_{t+1} (flies under the barrier wait)
    if (kh == 1) {
      const int tn = (t + 1 < T_) ? (t + 1) : t;
      Axh = xh + ((size_t)arow * T_ + tn) * D_ + (kg << 3);
      Axl = xl + ((size_t)arow * T_ + tn) * D_ + (kg << 3);
      XLD(p, 0)
    }

    // ---- single-aggregator barrier ----
    const unsigned tgt = (unsigned)(t + 1);
    if (tid == 0)
      __hip_atomic_store(&bar[bid], tgt, __ATOMIC_RELAXED,
                         __HIP_MEMORY_SCOPE_AGENT);
    if (bid == 0 && tid < 64) {
      // block 0 alone scans all 256 flags (1 KB/iter fabric load — cheap)
      const unsigned long long* fl = (const unsigned long long*)bar;
      for (;;) {
        unsigned long long v0 = __hip_atomic_load(fl + tid, __ATOMIC_RELAXED,
                                                  __HIP_MEMORY_SCOPE_AGENT);
        unsigned long long v1 = __hip_atomic_load(fl + 64 + tid, __ATOMIC_RELAXED,
                                                  __HIP_MEMORY_SCOPE_AGENT);
        bool ok = ((unsigned)v0 >= tgt) && ((unsigned)(v0 >> 32) >= tgt) &&
                  ((unsigned)v1 >= tgt) && ((unsigned)(v1 >> 32) >= tgt);
        if (__all((int)ok)) break;
      }
      if (tid == 0)
        __hip_atomic_store(rel, tgt, __ATOMIC_RELAXED, __HIP_MEMORY_SCOPE_AGENT);
    }
    if (tid == 0) {
      while (__hip_atomic_load(rel, __ATOMIC_RELAXED,
                               __HIP_MEMORY_SCOPE_AGENT) < tgt)
        __builtin_amdgcn_s_sleep(1);
    }
    __syncthreads();
  }
#undef XLD
#undef XCOMP
}

// ---------------------------------------------------------------------------
// Fallback (tiny ws): fused per-step VALU kernel (round-1 proven). Slow.
// ---------------------------------------------------------------------------
__global__ __launch_bounds__(256) void lstm_step_fb(
    const float* __restrict__ xt, const float* __restrict__ Wx,
    const float* __restrict__ Wh, const float* __restrict__ bias,
    const float* __restrict__ h_prev, long long hstride,
    float* __restrict__ cbuf, float* __restrict__ h_out, int first) {
  __shared__ float hS[32][128];
  __shared__ float wT[32][132];
  __shared__ float pre[32][34];
  const int tid = threadIdx.x;
  const int colblk = blockIdx.x & 127;
  const int nh = blockIdx.x >> 7;
  const int j0 = colblk << 3;
  const int n0 = nh << 5;
  const int ng = tid >> 4, cg2 = tid & 15;
  const int na = ng << 1, ca = cg2 << 1;

  float acc[2][2] = {{0.f, 0.f}, {0.f, 0.f}};

#pragma unroll
  for (int pr = 0; pr < 2; ++pr) {
    const float* src = (pr == 0) ? h_prev : xt;
    long long sstr = (pr == 0) ? hstride : (long long)T_ * D_;
    const float* W = (pr == 0) ? Wh : Wx;
    for (int k0 = 0; k0 < 1024; k0 += 128) {
      __syncthreads();
#pragma unroll
      for (int p = 0; p < 4; ++p) {
        int idx = tid + (p << 8);
        int r = idx >> 5, c4 = (idx & 31) << 2;
        *reinterpret_cast<float4*>(&hS[r][c4]) =
            *reinterpret_cast<const float4*>(src + (size_t)(n0 + r) * sstr + k0 + c4);
      }
#pragma unroll
      for (int p = 0; p < 4; ++p) {
        int idx = tid + (p << 8);
        int k = idx >> 3, sub = idx & 7;
        int g = sub >> 1, hf = (sub & 1) << 2;
        float4 v = *reinterpret_cast<const float4*>(
            W + (size_t)(k0 + k) * FH + g * H_ + j0 + hf);
        int cb = (g << 3) + hf;
        wT[cb][k] = v.x; wT[cb + 1][k] = v.y; wT[cb + 2][k] = v.z; wT[cb + 3][k] = v.w;
      }
      __syncthreads();
#pragma unroll
      for (int kk = 0; kk < 128; kk += 4) {
        float4 h0v = *reinterpret_cast<const float4*>(&hS[na][kk]);
        float4 h1v = *reinterpret_cast<const float4*>(&hS[na + 1][kk]);
        float4 w0 = *reinterpret_cast<const float4*>(&wT[ca][kk]);
        float4 w1 = *reinterpret_cast<const float4*>(&wT[ca + 1][kk]);
        acc[0][0] = fmaf(h0v.x, w0.x, acc[0][0]); acc[0][0] = fmaf(h0v.y, w0.y, acc[0][0]);
        acc[0][0] = fmaf(h0v.z, w0.z, acc[0][0]); acc[0][0] = fmaf(h0v.w, w0.w, acc[0][0]);
        acc[0][1] = fmaf(h0v.x, w1.x, acc[0][1]); acc[0][1] = fmaf(h0v.y, w1.y, acc[0][1]);
        acc[0][1] = fmaf(h0v.z, w1.z, acc[0][1]); acc[0][1] = fmaf(h0v.w, w1.w, acc[0][1]);
        acc[1][0] = fmaf(h1v.x, w0.x, acc[1][0]); acc[1][0] = fmaf(h1v.y, w0.y, acc[1][0]);
        acc[1][0] = fmaf(h1v.z, w0.z, acc[1][0]); acc[1][0] = fmaf(h1v.w, w0.w, acc[1][0]);
        acc[1][1] = fmaf(h1v.x, w1.x, acc[1][1]); acc[1][1] = fmaf(h1v.y, w1.y, acc[1][1]);
        acc[1][1] = fmaf(h1v.z, w1.z, acc[1][1]); acc[1][1] = fmaf(h1v.w, w1.w, acc[1][1]);
      }
    }
  }

  pre[na][ca] = acc[0][0];
  pre[na][ca + 1] = acc[0][1];
  pre[na + 1][ca] = acc[1][0];
  pre[na + 1][ca + 1] = acc[1][1];
  __syncthreads();

  const int nl = tid >> 3, jl = tid & 7;
  const int n = n0 + nl;
  const int jg = j0 + jl;
  float ai = pre[nl][jl] + bias[jg];
  float af = pre[nl][8 + jl] + bias[H_ + jg];
  float ao = pre[nl][16 + jl] + bias[2 * H_ + jg];
  float ag = pre[nl][24 + jl] + bias[3 * H_ + jg];
  float cp = first ? 0.0f : cbuf[n * H_ + jg];
  float iv = 1.f / (1.f + __expf(-ai));
  float fv = 1.f / (1.f + __expf(-af));
  float ov = 1.f / (1.f + __expf(-ao));
  float gv = tanhf(ag);
  float cn = fmaf(fv, cp, iv * gv);
  cbuf[n * H_ + jg] = cn;
  h_out[(size_t)n * ((size_t)T_ * H_) + jg] = ov * tanhf(cn);
}

// ---------------------------------------------------------------------------
extern "C" void kernel_launch(void* const* d_in, const int* in_sizes, int n_in,
                              void* d_out, int out_size, void* d_ws, size_t ws_size,
                              hipStream_t stream) {
  (void)in_sizes; (void)n_in; (void)out_size;
  const float* x  = (const float*)d_in[0];
  const float* h0 = (const float*)d_in[1];
  const float* Wx = (const float*)d_in[2];
  const float* Wh = (const float*)d_in[3];
  const float* b  = (const float*)d_in[4];
  float* out = (float*)d_out;

  const size_t MB = 1u << 20;
  char* p = (char*)d_ws;

  if (ws_size >= 300 * MB) {
    unsigned* bar = (unsigned*)p;               // flags[256] + rel @ +384
    ushort* Whh = (ushort*)(p + 1 * MB);
    ushort* Whl = (ushort*)(p + 9 * MB);
    ushort* Wxh = (ushort*)(p + 17 * MB);
    ushort* Wxl = (ushort*)(p + 25 * MB);
    uint32_t* hseq = (uint32_t*)(p + 33 * MB);  // 513 * 256 KB = 128.25 MB
    ushort* xh = (ushort*)(p + 168 * MB);       // 64 MB
    ushort* xl = (ushort*)(p + 232 * MB);       // 64 MB (ends at 296 MB)

    pack_w_k<<<dim3(2048), dim3(256), 0, stream>>>(Wh, Whh, Whl);
    pack_w_k<<<dim3(2048), dim3(256), 0, stream>>>(Wx, Wxh, Wxl);
    // x: 8,388,608 float4 -> 32768 blocks (zeroes barrier words)
    split_f32_k<<<dim3(32768), dim3(256), 0, stream>>>(x, xh, xl, bar);
    // h0 -> packed u32 into hseq[0]
    conv_h0pk_k<<<dim3(64), dim3(256), 0, stream>>>(h0, hseq);

    const unsigned SH = 2048 * 16 * 2 + 128 * 17 * 4;  // 74240 B
    hipFuncSetAttribute((const void*)lstm_persist_mfma,
                        hipFuncAttributeMaxDynamicSharedMemorySize, (int)SH);
    lstm_persist_mfma<<<dim3(256), dim3(512), SH, stream>>>(
        Whh, Whl, Wxh, Wxl, xh, xl, b, hseq, out, bar);
  } else {
    float* cbuf = (float*)p;  // 256 KB
    for (int t = 0; t < T_; ++t) {
      const float* hp = (t == 0) ? h0 : out + (size_t)(t - 1) * H_;
      long long hstr = (t == 0) ? (long long)H_ : (long long)T_ * H_;
      lstm_step_fb<<<dim3(256), dim3(256), 0, stream>>>(
          x + (size_t)t * D_, Wx, Wh, b, hp, hstr, cbuf,
          out + (size_t)t * H_, t == 0);
    }
  }
}

// Round 13
// 9307.884 us; speedup vs baseline: 1.2943x; 1.1593x over previous
//
#include <hip/hip_runtime.h>
#include <cstdint>
#include <cstddef>

#define N_ 64
#define T_ 512
#define D_ 1024
#define H_ 1024
#define FH 4096  // 4*H

typedef __attribute__((ext_vector_type(8))) short bf16x8;
typedef __attribute__((ext_vector_type(4))) float f32x4;

static __device__ __forceinline__ uint16_t f2bf_(float f) {
  union { float f; uint32_t u; } v; v.f = f;
  uint32_t u = v.u + 0x7FFFu + ((v.u >> 16) & 1u);
  return (uint16_t)(u >> 16);
}
static __device__ __forceinline__ float bf2f_(uint16_t s) {
  union { uint32_t u; float f; } v; v.u = ((uint32_t)s) << 16;
  return v.f;
}
// split u64 of two packed (hi:lo) elements into hi-pair / lo-pair u32s
static __device__ __forceinline__ void unpk2_(unsigned long long e,
                                              uint32_t& hi, uint32_t& lo) {
  uint32_t a = (uint32_t)e, b = (uint32_t)(e >> 32);
  hi = (a >> 16) | (b & 0xFFFF0000u);
  lo = (a & 0xFFFFu) | (b << 16);
}

// plain cacheable u64 load (addresses are write-once -> no stale-line hazard)
#define ALD(p) (*(p))

// ---------------------------------------------------------------------------
// Pack W [1024][4096] into MFMA B-fragment order, split bf16 hi/lo (proven).
// ---------------------------------------------------------------------------
__global__ __launch_bounds__(256) void pack_w_k(const float* __restrict__ W,
                                                ushort* __restrict__ hi,
                                                ushort* __restrict__ lo) {
  const int i = blockIdx.x * 256 + threadIdx.x;  // 524288 = 256*32*64
  const int lane = i & 63, kc = (i >> 6) & 31, bid = i >> 11;
  const int c = lane & 15;
  const int col = (c >> 2) * H_ + (bid << 2) + (c & 3);
  const int k0 = (kc << 5) + ((lane >> 4) << 3);
  const size_t o = ((size_t)(bid * 32 + kc) * 64 + lane) * 8;
#pragma unroll
  for (int e = 0; e < 8; ++e) {
    float v = W[(size_t)(k0 + e) * FH + col];
    ushort h = f2bf_(v);
    hi[o + e] = h;
    lo[o + e] = f2bf_(v - bf2f_(h));
  }
}

// ---------------------------------------------------------------------------
// x: f32 -> bf16 hi/lo planes. Block 0 zeroes the barrier words.
// ---------------------------------------------------------------------------
__global__ __launch_bounds__(256) void split_f32_k(const float* __restrict__ src,
                                                   ushort* __restrict__ hi,
                                                   ushort* __restrict__ lo,
                                                   unsigned* bar) {
  if (bar != nullptr && blockIdx.x == 0) {
    bar[threadIdx.x] = 0u;
    bar[256 + threadIdx.x] = 0u;
  }
  const size_t i = (size_t)blockIdx.x * 256 + threadIdx.x;
  float4 v = reinterpret_cast<const float4*>(src)[i];
  ushort4 h, l;
  h.x = f2bf_(v.x); l.x = f2bf_(v.x - bf2f_(h.x));
  h.y = f2bf_(v.y); l.y = f2bf_(v.y - bf2f_(h.y));
  h.z = f2bf_(v.z); l.z = f2bf_(v.z - bf2f_(h.z));
  h.w = f2bf_(v.w); l.w = f2bf_(v.w - bf2f_(h.w));
  reinterpret_cast<ushort4*>(hi)[i] = h;
  reinterpret_cast<ushort4*>(lo)[i] = l;
}

// h0 f32 -> packed u32 (hi16:lo16). 64 blocks x 256 thr x 4 elems.
__global__ __launch_bounds__(256) void conv_h0pk_k(const float* __restrict__ src,
                                                   uint32_t* __restrict__ dst) {
  const int i = blockIdx.x * 256 + threadIdx.x;  // 16384 float4s
  float4 v = reinterpret_cast<const float4*>(src)[i];
  uint4 o;
  { ushort h = f2bf_(v.x); o.x = ((uint32_t)h << 16) | f2bf_(v.x - bf2f_(h)); }
  { ushort h = f2bf_(v.y); o.y = ((uint32_t)h << 16) | f2bf_(v.y - bf2f_(h)); }
  { ushort h = f2bf_(v.z); o.z = ((uint32_t)h << 16) | f2bf_(v.z - bf2f_(h)); }
  { ushort h = f2bf_(v.w); o.w = ((uint32_t)h << 16) | f2bf_(v.w - bf2f_(h)); }
  reinterpret_cast<uint4*>(dst)[i] = o;
}

// ---------------------------------------------------------------------------
// Persistent fused LSTM scan. Key change vs r12: x@Wx is TEMPORALLY BLOCKED.
// x-waves (w 4..7) burst-compute xw for steps [t+4..t+7] every 4th step
// (Wx slice read once per 4 steps -> Wx L2 stream drops 4x; r10-r12's
// hidden ~6us/step L2-fill bottleneck). Results go to a 32 KB LDS ring
// (8 slabs x [64 n][4 jj][4 g] f32) — block-local, coherent via the step's
// __syncthreads, full split-bf16 precision. Prologue fills slabs 0..7.
// h-waves (w 0..3): full-K h@Wh, B from LDS, A = cacheable u64 loads of the
// unique-address hseq ring (r10-proven). Epilogue: pre + LDS ring + bias.
// Barrier: r12 single-aggregator (flag stores, block-0 scan, 1 release word).
// LDS 100.2 KB -> 1 block/CU, 256 blocks on 256 CUs (same co-residency).
// ---------------------------------------------------------------------------
__global__ __launch_bounds__(512, 2) void lstm_persist_mfma(
    const ushort* __restrict__ Whh_g, const ushort* __restrict__ Whl_g,
    const ushort* __restrict__ Wxh, const ushort* __restrict__ Wxl,
    const ushort* __restrict__ xh, const ushort* __restrict__ xl,
    const float* __restrict__ bias,
    uint32_t* __restrict__ hseq,
    float* __restrict__ out, unsigned* __restrict__ bar) {
  extern __shared__ char ldsraw[];
  bf16x8* const WhH = (bf16x8*)ldsraw;       // 2048 units (32 KB)
  bf16x8* const WhL = WhH + 2048;            // 2048 units (32 KB)
  float* const pre = (float*)(WhL + 2048);   // 64*17 floats (4352 B)
  float (*const xwr)[64][4][4] =
      (float(*)[64][4][4])(pre + 64 * 17);   // 8 slabs x 4 KB = 32 KB

  const int tid = threadIdx.x, bid = blockIdx.x;
  const int lane = tid & 63, w = tid >> 6;
  const int mt = w & 3;
  const int arow = (mt << 4) | (lane & 15);
  const int kg = lane >> 4;
  const int dc = lane & 15, dr = (lane >> 4) << 2;
  const int en = tid >> 2, ejj = tid & 3;

  unsigned* const rel = bar + 384;  // release word, own 128-B region

  float bias4[4] = {0.f, 0.f, 0.f, 0.f};
  float creg = 0.f;
  if (tid < 256) {
#pragma unroll
    for (int g = 0; g < 4; ++g) bias4[g] = bias[g * H_ + (bid << 2) + ejj];
  }

  // one-time Wh stage into LDS (identity copy of packed layout)
  {
    const bf16x8* gh = reinterpret_cast<const bf16x8*>(Whh_g) + (size_t)bid * 2048;
    const bf16x8* gl = reinterpret_cast<const bf16x8*>(Whl_g) + (size_t)bid * 2048;
#pragma unroll
    for (int r = 0; r < 4; ++r) {
      int u = tid + (r << 9);
      WhH[u] = gh[u];
      WhL[u] = gl[u];
    }
  }
  __syncthreads();

  // Wx global fragment bases (x-wave; L2/L3-resident, read 1x per 4 steps)
  const bf16x8* Bxh = reinterpret_cast<const bf16x8*>(Wxh) + (size_t)bid * 2048 + lane;
  const bf16x8* Bxl = reinterpret_cast<const bf16x8*>(Wxl) + (size_t)bid * 2048 + lane;

  // ---- x-burst: compute xw[tb..tb+3] into LDS ring slabs (tb..tb+3)&7 ----
  auto xburst = [&](int tb) {
    f32x4 xa0 = {0.f, 0.f, 0.f, 0.f};
    f32x4 xa1 = {0.f, 0.f, 0.f, 0.f};
    f32x4 xa2 = {0.f, 0.f, 0.f, 0.f};
    f32x4 xa3 = {0.f, 0.f, 0.f, 0.f};
    const ushort* axh = xh + ((size_t)arow * T_ + tb) * D_ + (kg << 3);
    const ushort* axl = xl + ((size_t)arow * T_ + tb) * D_ + (kg << 3);
#pragma unroll 4
    for (int kc = 0; kc < 32; ++kc) {
      bf16x8 bh = Bxh[kc << 6];
      bf16x8 bl = Bxl[kc << 6];
      bf16x8 a0h = *reinterpret_cast<const bf16x8*>(axh + (kc << 5));
      bf16x8 a0l = *reinterpret_cast<const bf16x8*>(axl + (kc << 5));
      bf16x8 a1h = *reinterpret_cast<const bf16x8*>(axh + D_ + (kc << 5));
      bf16x8 a1l = *reinterpret_cast<const bf16x8*>(axl + D_ + (kc << 5));
      bf16x8 a2h = *reinterpret_cast<const bf16x8*>(axh + 2 * D_ + (kc << 5));
      bf16x8 a2l = *reinterpret_cast<const bf16x8*>(axl + 2 * D_ + (kc << 5));
      bf16x8 a3h = *reinterpret_cast<const bf16x8*>(axh + 3 * D_ + (kc << 5));
      bf16x8 a3l = *reinterpret_cast<const bf16x8*>(axl + 3 * D_ + (kc << 5));
      xa0 = __builtin_amdgcn_mfma_f32_16x16x32_bf16(a0h, bh, xa0, 0, 0, 0);
      xa1 = __builtin_amdgcn_mfma_f32_16x16x32_bf16(a1h, bh, xa1, 0, 0, 0);
      xa2 = __builtin_amdgcn_mfma_f32_16x16x32_bf16(a2h, bh, xa2, 0, 0, 0);
      xa3 = __builtin_amdgcn_mfma_f32_16x16x32_bf16(a3h, bh, xa3, 0, 0, 0);
      xa0 = __builtin_amdgcn_mfma_f32_16x16x32_bf16(a0h, bl, xa0, 0, 0, 0);
      xa1 = __builtin_amdgcn_mfma_f32_16x16x32_bf16(a1h, bl, xa1, 0, 0, 0);
      xa2 = __builtin_amdgcn_mfma_f32_16x16x32_bf16(a2h, bl, xa2, 0, 0, 0);
      xa3 = __builtin_amdgcn_mfma_f32_16x16x32_bf16(a3h, bl, xa3, 0, 0, 0);
      xa0 = __builtin_amdgcn_mfma_f32_16x16x32_bf16(a0l, bh, xa0, 0, 0, 0);
      xa1 = __builtin_amdgcn_mfma_f32_16x16x32_bf16(a1l, bh, xa1, 0, 0, 0);
      xa2 = __builtin_amdgcn_mfma_f32_16x16x32_bf16(a2l, bh, xa2, 0, 0, 0);
      xa3 = __builtin_amdgcn_mfma_f32_16x16x32_bf16(a3l, bh, xa3, 0, 0, 0);
    }
    // D layout: col = lane&15, row = (lane>>4)*4 + r (m89-verified)
    const int g = dc >> 2, jj = dc & 3;
#pragma unroll
    for (int r = 0; r < 4; ++r) {
      const int row = (mt << 4) + dr + r;
      xwr[(tb + 0) & 7][row][jj][g] = xa0[r];
      xwr[(tb + 1) & 7][row][jj][g] = xa1[r];
      xwr[(tb + 2) & 7][row][jj][g] = xa2[r];
      xwr[(tb + 3) & 7][row][jj][g] = xa3[r];
    }
  };

  // prologue: x-waves fill ring slabs 0..7 (h-waves proceed to step 0;
  // the step's first __syncthreads orders ring-write -> epilogue-read)
  if (w >= 4) {
    xburst(0);
    xburst(4);
  }

  for (int t = 0; t < T_; ++t) {
    if (w < 4) {
      // ---- h @ Wh : A via cacheable u64 loads of hseq[t], B from LDS ----
      f32x4 acc0 = {0.f, 0.f, 0.f, 0.f};
      f32x4 acc1 = {0.f, 0.f, 0.f, 0.f};
      const unsigned long long* Apk =
          (const unsigned long long*)(hseq + (size_t)t * 65536) +
          arow * 512 + kg * 4;

      unsigned long long pa0, pa1, pa2, pa3, pb0, pb1, pb2, pb3;
      unsigned long long pc0, pc1, pc2, pc3, pd0, pd1, pd2, pd3;
      unsigned long long qa0, qa1, qa2, qa3, qb0, qb1, qb2, qb3;
      unsigned long long qc0, qc1, qc2, qc3, qd0, qd1, qd2, qd3;

#define HLD(P, CH)                                                            \
  {                                                                           \
    const unsigned long long* ap_ = Apk + ((CH) << 6);                        \
    P##a0 = ALD(ap_ + 0);  P##a1 = ALD(ap_ + 1);                              \
    P##a2 = ALD(ap_ + 2);  P##a3 = ALD(ap_ + 3);                              \
    P##b0 = ALD(ap_ + 16); P##b1 = ALD(ap_ + 17);                             \
    P##b2 = ALD(ap_ + 18); P##b3 = ALD(ap_ + 19);                             \
    P##c0 = ALD(ap_ + 32); P##c1 = ALD(ap_ + 33);                             \
    P##c2 = ALD(ap_ + 34); P##c3 = ALD(ap_ + 35);                             \
    P##d0 = ALD(ap_ + 48); P##d1 = ALD(ap_ + 49);                             \
    P##d2 = ALD(ap_ + 50); P##d3 = ALD(ap_ + 51);                             \
  }

#define HKC(E0, E1, E2, E3, KCG, ACC)                                         \
  {                                                                           \
    union { uint32_t u[4]; bf16x8 v; } fh_, fl_;                              \
    unpk2_(E0, fh_.u[0], fl_.u[0]);                                           \
    unpk2_(E1, fh_.u[1], fl_.u[1]);                                           \
    unpk2_(E2, fh_.u[2], fl_.u[2]);                                           \
    unpk2_(E3, fh_.u[3], fl_.u[3]);                                           \
    bf16x8 bh_ = WhH[((KCG) << 6) + lane];                                    \
    bf16x8 bl_ = WhL[((KCG) << 6) + lane];                                    \
    ACC = __builtin_amdgcn_mfma_f32_16x16x32_bf16(fh_.v, bh_, ACC, 0, 0, 0);  \
    ACC = __builtin_amdgcn_mfma_f32_16x16x32_bf16(fh_.v, bl_, ACC, 0, 0, 0);  \
    ACC = __builtin_amdgcn_mfma_f32_16x16x32_bf16(fl_.v, bh_, ACC, 0, 0, 0);  \
  }

#define HCOMP(P, CH)                                                          \
  HKC(P##a0, P##a1, P##a2, P##a3, (CH) * 4 + 0, acc0)                         \
  HKC(P##b0, P##b1, P##b2, P##b3, (CH) * 4 + 1, acc1)                         \
  HKC(P##c0, P##c1, P##c2, P##c3, (CH) * 4 + 2, acc0)                         \
  HKC(P##d0, P##d1, P##d2, P##d3, (CH) * 4 + 3, acc1)

      HLD(p, 0)
      HLD(q, 1) HCOMP(p, 0)
      HLD(p, 2) HCOMP(q, 1)
      HLD(q, 3) HCOMP(p, 2)
      HLD(p, 4) HCOMP(q, 3)
      HLD(q, 5) HCOMP(p, 4)
      HLD(p, 6) HCOMP(q, 5)
      HLD(q, 7) HCOMP(p, 6)
      HCOMP(q, 7)
#undef HLD
#undef HKC
#undef HCOMP

      f32x4 accs = acc0 + acc1;
#pragma unroll
      for (int r = 0; r < 4; ++r)
        pre[((mt << 4) + dr + r) * 17 + dc] = accs[r];
    } else {
      // ---- x-waves: burst-compute xw[t+4..t+7] every 4th step ----
      if (t != 0 && (t & 3) == 0 && t + 4 < T_) xburst(t + 4);
    }
    __syncthreads();

    if (tid < 256) {
      const float* xvp = &xwr[t & 7][en][ejj][0];
      float a[4];
#pragma unroll
      for (int g = 0; g < 4; ++g)
        a[g] = pre[en * 17 + (g << 2) + ejj] + xvp[g] + bias4[g];
      float iv = 1.f / (1.f + __expf(-a[0]));
      float fv = 1.f / (1.f + __expf(-a[1]));
      float ov = 1.f / (1.f + __expf(-a[2]));
      float gv = tanhf(a[3]);
      creg = fmaf(fv, creg, iv * gv);
      float hn = ov * tanhf(creg);
      out[(size_t)en * ((size_t)T_ * H_) + (size_t)t * H_ + (bid << 2) + ejj] = hn;
      ushort hh = f2bf_(hn);
      uint32_t pk = ((uint32_t)hh << 16) | f2bf_(hn - bf2f_(hh));
      __hip_atomic_store(&hseq[(size_t)(t + 1) * 65536 + en * H_ + (bid << 2) + ejj],
                         pk, __ATOMIC_RELAXED, __HIP_MEMORY_SCOPE_AGENT);
    }

    // ---- drain h stores, then single-aggregator barrier (r12-proven) ----
    asm volatile("s_waitcnt vmcnt(0)" ::: "memory");
    __syncthreads();

    const unsigned tgt = (unsigned)(t + 1);
    if (tid == 0)
      __hip_atomic_store(&bar[bid], tgt, __ATOMIC_RELAXED,
                         __HIP_MEMORY_SCOPE_AGENT);
    if (bid == 0 && tid < 64) {
      const unsigned long long* fl = (const unsigned long long*)bar;
      for (;;) {
        unsigned long long v0 = __hip_atomic_load(fl + tid, __ATOMIC_RELAXED,
                                                  __HIP_MEMORY_SCOPE_AGENT);
        unsigned long long v1 = __hip_atomic_load(fl + 64 + tid, __ATOMIC_RELAXED,
                                                  __HIP_MEMORY_SCOPE_AGENT);
        bool ok = ((unsigned)v0 >= tgt) && ((unsigned)(v0 >> 32) >= tgt) &&
                  ((unsigned)v1 >= tgt) && ((unsigned)(v1 >> 32) >= tgt);
        if (__all((int)ok)) break;
      }
      if (tid == 0)
        __hip_atomic_store(rel, tgt, __ATOMIC_RELAXED, __HIP_MEMORY_SCOPE_AGENT);
    }
    if (tid == 0) {
      while (__hip_atomic_load(rel, __ATOMIC_RELAXED,
                               __HIP_MEMORY_SCOPE_AGENT) < tgt)
        __builtin_amdgcn_s_sleep(1);
    }
    __syncthreads();
  }
}

// ---------------------------------------------------------------------------
// Fallback (tiny ws): fused per-step VALU kernel (round-1 proven). Slow.
// ---------------------------------------------------------------------------
__global__ __launch_bounds__(256) void lstm_step_fb(
    const float* __restrict__ xt, const float* __restrict__ Wx,
    const float* __restrict__ Wh, const float* __restrict__ bias,
    const float* __restrict__ h_prev, long long hstride,
    float* __restrict__ cbuf, float* __restrict__ h_out, int first) {
  __shared__ float hS[32][128];
  __shared__ float wT[32][132];
  __shared__ float pre[32][34];
  const int tid = threadIdx.x;
  const int colblk = blockIdx.x & 127;
  const int nh = blockIdx.x >> 7;
  const int j0 = colblk << 3;
  const int n0 = nh << 5;
  const int ng = tid >> 4, cg2 = tid & 15;
  const int na = ng << 1, ca = cg2 << 1;

  float acc[2][2] = {{0.f, 0.f}, {0.f, 0.f}};

#pragma unroll
  for (int pr = 0; pr < 2; ++pr) {
    const float* src = (pr == 0) ? h_prev : xt;
    long long sstr = (pr == 0) ? hstride : (long long)T_ * D_;
    const float* W = (pr == 0) ? Wh : Wx;
    for (int k0 = 0; k0 < 1024; k0 += 128) {
      __syncthreads();
#pragma unroll
      for (int p = 0; p < 4; ++p) {
        int idx = tid + (p << 8);
        int r = idx >> 5, c4 = (idx & 31) << 2;
        *reinterpret_cast<float4*>(&hS[r][c4]) =
            *reinterpret_cast<const float4*>(src + (size_t)(n0 + r) * sstr + k0 + c4);
      }
#pragma unroll
      for (int p = 0; p < 4; ++p) {
        int idx = tid + (p << 8);
        int k = idx >> 3, sub = idx & 7;
        int g = sub >> 1, hf = (sub & 1) << 2;
        float4 v = *reinterpret_cast<const float4*>(
            W + (size_t)(k0 + k) * FH + g * H_ + j0 + hf);
        int cb = (g << 3) + hf;
        wT[cb][k] = v.x; wT[cb + 1][k] = v.y; wT[cb + 2][k] = v.z; wT[cb + 3][k] = v.w;
      }
      __syncthreads();
#pragma unroll
      for (int kk = 0; kk < 128; kk += 4) {
        float4 h0v = *reinterpret_cast<const float4*>(&hS[na][kk]);
        float4 h1v = *reinterpret_cast<const float4*>(&hS[na + 1][kk]);
        float4 w0 = *reinterpret_cast<const float4*>(&wT[ca][kk]);
        float4 w1 = *reinterpret_cast<const float4*>(&wT[ca + 1][kk]);
        acc[0][0] = fmaf(h0v.x, w0.x, acc[0][0]); acc[0][0] = fmaf(h0v.y, w0.y, acc[0][0]);
        acc[0][0] = fmaf(h0v.z, w0.z, acc[0][0]); acc[0][0] = fmaf(h0v.w, w0.w, acc[0][0]);
        acc[0][1] = fmaf(h0v.x, w1.x, acc[0][1]); acc[0][1] = fmaf(h0v.y, w1.y, acc[0][1]);
        acc[0][1] = fmaf(h0v.z, w1.z, acc[0][1]); acc[0][1] = fmaf(h0v.w, w1.w, acc[0][1]);
        acc[1][0] = fmaf(h1v.x, w0.x, acc[1][0]); acc[1][0] = fmaf(h1v.y, w0.y, acc[1][0]);
        acc[1][0] = fmaf(h1v.z, w0.z, acc[1][0]); acc[1][0] = fmaf(h1v.w, w0.w, acc[1][0]);
        acc[1][1] = fmaf(h1v.x, w1.x, acc[1][1]); acc[1][1] = fmaf(h1v.y, w1.y, acc[1][1]);
        acc[1][1] = fmaf(h1v.z, w1.z, acc[1][1]); acc[1][1] = fmaf(h1v.w, w1.w, acc[1][1]);
      }
    }
  }

  pre[na][ca] = acc[0][0];
  pre[na][ca + 1] = acc[0][1];
  pre[na + 1][ca] = acc[1][0];
  pre[na + 1][ca + 1] = acc[1][1];
  __syncthreads();

  const int nl = tid >> 3, jl = tid & 7;
  const int n = n0 + nl;
  const int jg = j0 + jl;
  float ai = pre[nl][jl] + bias[jg];
  float af = pre[nl][8 + jl] + bias[H_ + jg];
  float ao = pre[nl][16 + jl] + bias[2 * H_ + jg];
  float ag = pre[nl][24 + jl] + bias[3 * H_ + jg];
  float cp = first ? 0.0f : cbuf[n * H_ + jg];
  float iv = 1.f / (1.f + __expf(-ai));
  float fv = 1.f / (1.f + __expf(-af));
  float ov = 1.f / (1.f + __expf(-ao));
  float gv = tanhf(ag);
  float cn = fmaf(fv, cp, iv * gv);
  cbuf[n * H_ + jg] = cn;
  h_out[(size_t)n * ((size_t)T_ * H_) + jg] = ov * tanhf(cn);
}

// ---------------------------------------------------------------------------
extern "C" void kernel_launch(void* const* d_in, const int* in_sizes, int n_in,
                              void* d_out, int out_size, void* d_ws, size_t ws_size,
                              hipStream_t stream) {
  (void)in_sizes; (void)n_in; (void)out_size;
  const float* x  = (const float*)d_in[0];
  const float* h0 = (const float*)d_in[1];
  const float* Wx = (const float*)d_in[2];
  const float* Wh = (const float*)d_in[3];
  const float* b  = (const float*)d_in[4];
  float* out = (float*)d_out;

  const size_t MB = 1u << 20;
  char* p = (char*)d_ws;

  if (ws_size >= 300 * MB) {
    unsigned* bar = (unsigned*)p;               // flags[256] + rel @ +384
    ushort* Whh = (ushort*)(p + 1 * MB);
    ushort* Whl = (ushort*)(p + 9 * MB);
    ushort* Wxh = (ushort*)(p + 17 * MB);
    ushort* Wxl = (ushort*)(p + 25 * MB);
    uint32_t* hseq = (uint32_t*)(p + 33 * MB);  // 513 * 256 KB = 128.25 MB
    ushort* xh = (ushort*)(p + 168 * MB);       // 64 MB
    ushort* xl = (ushort*)(p + 232 * MB);       // 64 MB (ends at 296 MB)

    pack_w_k<<<dim3(2048), dim3(256), 0, stream>>>(Wh, Whh, Whl);
    pack_w_k<<<dim3(2048), dim3(256), 0, stream>>>(Wx, Wxh, Wxl);
    // x: 8,388,608 float4 -> 32768 blocks (zeroes barrier words)
    split_f32_k<<<dim3(32768), dim3(256), 0, stream>>>(x, xh, xl, bar);
    // h0 -> packed u32 into hseq[0]
    conv_h0pk_k<<<dim3(64), dim3(256), 0, stream>>>(h0, hseq);

    const unsigned SH = 65536 + 64 * 17 * 4 + 8 * 64 * 16 * 4;  // 102656 B
    hipFuncSetAttribute((const void*)lstm_persist_mfma,
                        hipFuncAttributeMaxDynamicSharedMemorySize, (int)SH);
    lstm_persist_mfma<<<dim3(256), dim3(512), SH, stream>>>(
        Whh, Whl, Wxh, Wxl, xh, xl, b, hseq, out, bar);
  } else {
    float* cbuf = (float*)p;  // 256 KB
    for (int t = 0; t < T_; ++t) {
      const float* hp = (t == 0) ? h0 : out + (size_t)(t - 1) * H_;
      long long hstr = (t == 0) ? (long long)H_ : (long long)T_ * H_;
      lstm_step_fb<<<dim3(256), dim3(256), 0, stream>>>(
          x + (size_t)t * D_, Wx, Wh, b, hp, hstr, cbuf,
          out + (size_t)t * H_, t == 0);
    }
  }
}

// Round 14
// 9110.147 us; speedup vs baseline: 1.3224x; 1.0217x over previous
//
#include <hip/hip_runtime.h>
#include <cstdint>
#include <cstddef>

#define N_ 64
#define T_ 512
#define D_ 1024
#define H_ 1024
#define FH 4096  // 4*H

typedef __attribute__((ext_vector_type(8))) short bf16x8;
typedef __attribute__((ext_vector_type(4))) float f32x4;

static __device__ __forceinline__ uint16_t f2bf_(float f) {
  union { float f; uint32_t u; } v; v.f = f;
  uint32_t u = v.u + 0x7FFFu + ((v.u >> 16) & 1u);
  return (uint16_t)(u >> 16);
}
static __device__ __forceinline__ float bf2f_(uint16_t s) {
  union { uint32_t u; float f; } v; v.u = ((uint32_t)s) << 16;
  return v.f;
}
// split u64 of two packed (hi:lo) elements into hi-pair / lo-pair u32s
static __device__ __forceinline__ void unpk2_(unsigned long long e,
                                              uint32_t& hi, uint32_t& lo) {
  uint32_t a = (uint32_t)e, b = (uint32_t)(e >> 32);
  hi = (a >> 16) | (b & 0xFFFF0000u);
  lo = (a & 0xFFFFu) | (b << 16);
}

// plain cacheable u64 load (addresses are write-once -> no stale-line hazard)
#define ALD(p) (*(p))

// ---------------------------------------------------------------------------
// Pack W [1024][4096] into MFMA B-fragment order, split bf16 hi/lo (proven).
// ---------------------------------------------------------------------------
__global__ __launch_bounds__(256) void pack_w_k(const float* __restrict__ W,
                                                ushort* __restrict__ hi,
                                                ushort* __restrict__ lo) {
  const int i = blockIdx.x * 256 + threadIdx.x;  // 524288 = 256*32*64
  const int lane = i & 63, kc = (i >> 6) & 31, bid = i >> 11;
  const int c = lane & 15;
  const int col = (c >> 2) * H_ + (bid << 2) + (c & 3);
  const int k0 = (kc << 5) + ((lane >> 4) << 3);
  const size_t o = ((size_t)(bid * 32 + kc) * 64 + lane) * 8;
#pragma unroll
  for (int e = 0; e < 8; ++e) {
    float v = W[(size_t)(k0 + e) * FH + col];
    ushort h = f2bf_(v);
    hi[o + e] = h;
    lo[o + e] = f2bf_(v - bf2f_(h));
  }
}

// ---------------------------------------------------------------------------
// x: f32 -> bf16 hi/lo planes. Block 0 zeroes the barrier words.
// ---------------------------------------------------------------------------
__global__ __launch_bounds__(256) void split_f32_k(const float* __restrict__ src,
                                                   ushort* __restrict__ hi,
                                                   ushort* __restrict__ lo,
                                                   unsigned* bar) {
  if (bar != nullptr && blockIdx.x == 0) {
    bar[threadIdx.x] = 0u;
    bar[256 + threadIdx.x] = 0u;
  }
  const size_t i = (size_t)blockIdx.x * 256 + threadIdx.x;
  float4 v = reinterpret_cast<const float4*>(src)[i];
  ushort4 h, l;
  h.x = f2bf_(v.x); l.x = f2bf_(v.x - bf2f_(h.x));
  h.y = f2bf_(v.y); l.y = f2bf_(v.y - bf2f_(h.y));
  h.z = f2bf_(v.z); l.z = f2bf_(v.z - bf2f_(h.z));
  h.w = f2bf_(v.w); l.w = f2bf_(v.w - bf2f_(h.w));
  reinterpret_cast<ushort4*>(hi)[i] = h;
  reinterpret_cast<ushort4*>(lo)[i] = l;
}

// h0 f32 -> packed u32 (hi16:lo16). 64 blocks x 256 thr x 4 elems.
__global__ __launch_bounds__(256) void conv_h0pk_k(const float* __restrict__ src,
                                                   uint32_t* __restrict__ dst) {
  const int i = blockIdx.x * 256 + threadIdx.x;  // 16384 float4s
  float4 v = reinterpret_cast<const float4*>(src)[i];
  uint4 o;
  { ushort h = f2bf_(v.x); o.x = ((uint32_t)h << 16) | f2bf_(v.x - bf2f_(h)); }
  { ushort h = f2bf_(v.y); o.y = ((uint32_t)h << 16) | f2bf_(v.y - bf2f_(h)); }
  { ushort h = f2bf_(v.z); o.z = ((uint32_t)h << 16) | f2bf_(v.z - bf2f_(h)); }
  { ushort h = f2bf_(v.w); o.w = ((uint32_t)h << 16) | f2bf_(v.w - bf2f_(h)); }
  reinterpret_cast<uint4*>(dst)[i] = o;
}

// ---------------------------------------------------------------------------
// Persistent fused LSTM scan. Changes vs r13:
// - ALL 8 waves do h@Wh: wave=(mt=w&3, kh=w>>2) M x K-half split. Per-wave
//   serial load chain 8->4 clusters, 2x load parallelism. pre = [128][17]
//   two-slab reduce (r7-r9 proven layout).
// - ALL 8 waves do the x-burst (wave=(mt2=w&3, t-pair=w>>2), full K, direct
//   slab store). Burst moved AFTER the arrival-flag store, BEFORE the release
//   poll: on burst steps the barrier chain hides under the burst.
// - __launch_bounds__(512,1): prevent r13's 60-VGPR pipeline collapse.
// Everything else r13-proven: unique-address hseq ring (cacheable reads,
// write-through stores), 32 KB LDS xw ring, single-aggregator barrier.
// LDS 104.5 KB -> 1 block/CU, 256 blocks on 256 CUs.
// ---------------------------------------------------------------------------
__global__ __launch_bounds__(512, 1) void lstm_persist_mfma(
    const ushort* __restrict__ Whh_g, const ushort* __restrict__ Whl_g,
    const ushort* __restrict__ Wxh, const ushort* __restrict__ Wxl,
    const ushort* __restrict__ xh, const ushort* __restrict__ xl,
    const float* __restrict__ bias,
    uint32_t* __restrict__ hseq,
    float* __restrict__ out, unsigned* __restrict__ bar) {
  extern __shared__ char ldsraw[];
  bf16x8* const WhH = (bf16x8*)ldsraw;       // 2048 units (32 KB)
  bf16x8* const WhL = WhH + 2048;            // 2048 units (32 KB)
  float* const pre = (float*)(WhL + 2048);   // 128*17 floats (8704 B)
  float (*const xwr)[64][4][4] =
      (float(*)[64][4][4])(pre + 128 * 17);  // 8 slabs x 4 KB = 32 KB

  const int tid = threadIdx.x, bid = blockIdx.x;
  const int lane = tid & 63, w = tid >> 6;
  const int mt = w & 3, kh = w >> 2;         // h-phase: M-tile x K-half
  const int khb = kh << 4;                   // kc base of this K-half
  const int arow = (mt << 4) | (lane & 15);
  const int kg = lane >> 4;
  const int dc = lane & 15, dr = (lane >> 4) << 2;
  const int en = tid >> 2, ejj = tid & 3;

  unsigned* const rel = bar + 384;  // release word, own 128-B region

  float bias4[4] = {0.f, 0.f, 0.f, 0.f};
  float creg = 0.f;
  if (tid < 256) {
#pragma unroll
    for (int g = 0; g < 4; ++g) bias4[g] = bias[g * H_ + (bid << 2) + ejj];
  }

  // one-time Wh stage into LDS (identity copy of packed layout)
  {
    const bf16x8* gh = reinterpret_cast<const bf16x8*>(Whh_g) + (size_t)bid * 2048;
    const bf16x8* gl = reinterpret_cast<const bf16x8*>(Whl_g) + (size_t)bid * 2048;
#pragma unroll
    for (int r = 0; r < 4; ++r) {
      int u = tid + (r << 9);
      WhH[u] = gh[u];
      WhL[u] = gl[u];
    }
  }
  __syncthreads();

  // Wx global fragment bases (L2/L3-hot; read once per 4 steps per wave)
  const bf16x8* Bxh = reinterpret_cast<const bf16x8*>(Wxh) + (size_t)bid * 2048 + lane;
  const bf16x8* Bxl = reinterpret_cast<const bf16x8*>(Wxl) + (size_t)bid * 2048 + lane;

  // ---- x-burst: all 8 waves; wave = (mt2 = w&3, tp = w>>2) covers
  //      timesteps tb+2*tp, tb+2*tp+1 at full K for its 16 rows ----
  auto xburst = [&](int tb) {
    const int mt2 = mt;            // w&3
    const int t0 = tb + (kh << 1); // w>>2 -> t-pair
    const int t1 = t0 + 1;
    const int row = (mt2 << 4) | (lane & 15);
    const ushort* a0h = xh + ((size_t)row * T_ + t0) * D_ + (kg << 3);
    const ushort* a0l = xl + ((size_t)row * T_ + t0) * D_ + (kg << 3);
    const ushort* a1h = xh + ((size_t)row * T_ + t1) * D_ + (kg << 3);
    const ushort* a1l = xl + ((size_t)row * T_ + t1) * D_ + (kg << 3);
    f32x4 xa0 = {0.f, 0.f, 0.f, 0.f};
    f32x4 xa1 = {0.f, 0.f, 0.f, 0.f};
#pragma unroll 4
    for (int kc = 0; kc < 32; ++kc) {
      bf16x8 bh = Bxh[kc << 6];
      bf16x8 bl = Bxl[kc << 6];
      bf16x8 h0 = *reinterpret_cast<const bf16x8*>(a0h + (kc << 5));
      bf16x8 l0 = *reinterpret_cast<const bf16x8*>(a0l + (kc << 5));
      bf16x8 h1 = *reinterpret_cast<const bf16x8*>(a1h + (kc << 5));
      bf16x8 l1 = *reinterpret_cast<const bf16x8*>(a1l + (kc << 5));
      xa0 = __builtin_amdgcn_mfma_f32_16x16x32_bf16(h0, bh, xa0, 0, 0, 0);
      xa1 = __builtin_amdgcn_mfma_f32_16x16x32_bf16(h1, bh, xa1, 0, 0, 0);
      xa0 = __builtin_amdgcn_mfma_f32_16x16x32_bf16(h0, bl, xa0, 0, 0, 0);
      xa1 = __builtin_amdgcn_mfma_f32_16x16x32_bf16(h1, bl, xa1, 0, 0, 0);
      xa0 = __builtin_amdgcn_mfma_f32_16x16x32_bf16(l0, bh, xa0, 0, 0, 0);
      xa1 = __builtin_amdgcn_mfma_f32_16x16x32_bf16(l1, bh, xa1, 0, 0, 0);
    }
    // D layout (m89-verified): col = lane&15, row = (lane>>4)*4 + r
    const int g = dc >> 2, jj = dc & 3;
#pragma unroll
    for (int r = 0; r < 4; ++r) {
      const int rw = (mt2 << 4) + dr + r;
      xwr[t0 & 7][rw][jj][g] = xa0[r];
      xwr[t1 & 7][rw][jj][g] = xa1[r];
    }
  };

  // prologue: fill ring slabs 0..7 (step-0's first __syncthreads orders
  // these LDS writes before the first epilogue read)
  xburst(0);
  xburst(4);

  for (int t = 0; t < T_; ++t) {
    // ---- h @ Wh on ALL waves: wave's K-half, A = cacheable u64 loads ----
    {
      f32x4 acc0 = {0.f, 0.f, 0.f, 0.f};
      f32x4 acc1 = {0.f, 0.f, 0.f, 0.f};
      const unsigned long long* Apk =
          (const unsigned long long*)(hseq + (size_t)t * 65536) +
          arow * 512 + kg * 4 + (kh << 8);

      unsigned long long pa0, pa1, pa2, pa3, pb0, pb1, pb2, pb3;
      unsigned long long pc0, pc1, pc2, pc3, pd0, pd1, pd2, pd3;
      unsigned long long qa0, qa1, qa2, qa3, qb0, qb1, qb2, qb3;
      unsigned long long qc0, qc1, qc2, qc3, qd0, qd1, qd2, qd3;

#define HLD(P, CH)                                                            \
  {                                                                           \
    const unsigned long long* ap_ = Apk + ((CH) << 6);                        \
    P##a0 = ALD(ap_ + 0);  P##a1 = ALD(ap_ + 1);                              \
    P##a2 = ALD(ap_ + 2);  P##a3 = ALD(ap_ + 3);                              \
    P##b0 = ALD(ap_ + 16); P##b1 = ALD(ap_ + 17);                             \
    P##b2 = ALD(ap_ + 18); P##b3 = ALD(ap_ + 19);                             \
    P##c0 = ALD(ap_ + 32); P##c1 = ALD(ap_ + 33);                             \
    P##c2 = ALD(ap_ + 34); P##c3 = ALD(ap_ + 35);                             \
    P##d0 = ALD(ap_ + 48); P##d1 = ALD(ap_ + 49);                             \
    P##d2 = ALD(ap_ + 50); P##d3 = ALD(ap_ + 51);                             \
  }

#define HKC(E0, E1, E2, E3, KCG, ACC)                                         \
  {                                                                           \
    union { uint32_t u[4]; bf16x8 v; } fh_, fl_;                              \
    unpk2_(E0, fh_.u[0], fl_.u[0]);                                           \
    unpk2_(E1, fh_.u[1], fl_.u[1]);                                           \
    unpk2_(E2, fh_.u[2], fl_.u[2]);                                           \
    unpk2_(E3, fh_.u[3], fl_.u[3]);                                           \
    bf16x8 bh_ = WhH[((KCG) << 6) + lane];                                    \
    bf16x8 bl_ = WhL[((KCG) << 6) + lane];                                    \
    ACC = __builtin_amdgcn_mfma_f32_16x16x32_bf16(fh_.v, bh_, ACC, 0, 0, 0);  \
    ACC = __builtin_amdgcn_mfma_f32_16x16x32_bf16(fh_.v, bl_, ACC, 0, 0, 0);  \
    ACC = __builtin_amdgcn_mfma_f32_16x16x32_bf16(fl_.v, bh_, ACC, 0, 0, 0);  \
  }

#define HCOMP(P, CH)                                                          \
  HKC(P##a0, P##a1, P##a2, P##a3, khb + (CH) * 4 + 0, acc0)                   \
  HKC(P##b0, P##b1, P##b2, P##b3, khb + (CH) * 4 + 1, acc1)                   \
  HKC(P##c0, P##c1, P##c2, P##c3, khb + (CH) * 4 + 2, acc0)                   \
  HKC(P##d0, P##d1, P##d2, P##d3, khb + (CH) * 4 + 3, acc1)

      HLD(p, 0)
      HLD(q, 1) HCOMP(p, 0)
      HLD(p, 2) HCOMP(q, 1)
      HLD(q, 3) HCOMP(p, 2)
      HCOMP(q, 3)
#undef HLD
#undef HKC
#undef HCOMP

      f32x4 accs = acc0 + acc1;
      // pre slab: rows [kh*64 + mt*16 + dr + r], two-slab K reduce in epilogue
#pragma unroll
      for (int r = 0; r < 4; ++r)
        pre[((kh << 6) + (mt << 4) + dr + r) * 17 + dc] = accs[r];
    }
    __syncthreads();

    if (tid < 256) {
      const float* xvp = &xwr[t & 7][en][ejj][0];
      float a[4];
#pragma unroll
      for (int g = 0; g < 4; ++g)
        a[g] = pre[en * 17 + (g << 2) + ejj] +
               pre[(64 + en) * 17 + (g << 2) + ejj] + xvp[g] + bias4[g];
      float iv = 1.f / (1.f + __expf(-a[0]));
      float fv = 1.f / (1.f + __expf(-a[1]));
      float ov = 1.f / (1.f + __expf(-a[2]));
      float gv = tanhf(a[3]);
      creg = fmaf(fv, creg, iv * gv);
      float hn = ov * tanhf(creg);
      out[(size_t)en * ((size_t)T_ * H_) + (size_t)t * H_ + (bid << 2) + ejj] = hn;
      ushort hh = f2bf_(hn);
      uint32_t pk = ((uint32_t)hh << 16) | f2bf_(hn - bf2f_(hh));
      __hip_atomic_store(&hseq[(size_t)(t + 1) * 65536 + en * H_ + (bid << 2) + ejj],
                         pk, __ATOMIC_RELAXED, __HIP_MEMORY_SCOPE_AGENT);
    }

    // ---- drain h stores, then arrive ----
    asm volatile("s_waitcnt vmcnt(0)" ::: "memory");
    __syncthreads();

    const unsigned tgt = (unsigned)(t + 1);
    if (tid == 0)
      __hip_atomic_store(&bar[bid], tgt, __ATOMIC_RELAXED,
                         __HIP_MEMORY_SCOPE_AGENT);

    // ---- x-burst every 4th step, AFTER arrival: hides under the barrier ----
    if (t != 0 && (t & 3) == 0 && t + 4 < T_) xburst(t + 4);

    // ---- single-aggregator barrier (r12-proven) ----
    if (bid == 0 && tid < 64) {
      const unsigned long long* fl = (const unsigned long long*)bar;
      for (;;) {
        unsigned long long v0 = __hip_atomic_load(fl + tid, __ATOMIC_RELAXED,
                                                  __HIP_MEMORY_SCOPE_AGENT);
        unsigned long long v1 = __hip_atomic_load(fl + 64 + tid, __ATOMIC_RELAXED,
                                                  __HIP_MEMORY_SCOPE_AGENT);
        bool ok = ((unsigned)v0 >= tgt) && ((unsigned)(v0 >> 32) >= tgt) &&
                  ((unsigned)v1 >= tgt) && ((unsigned)(v1 >> 32) >= tgt);
        if (__all((int)ok)) break;
      }
      if (tid == 0)
        __hip_atomic_store(rel, tgt, __ATOMIC_RELAXED, __HIP_MEMORY_SCOPE_AGENT);
    }
    if (tid == 0) {
      while (__hip_atomic_load(rel, __ATOMIC_RELAXED,
                               __HIP_MEMORY_SCOPE_AGENT) < tgt)
        __builtin_amdgcn_s_sleep(1);
    }
    __syncthreads();
  }
}

// ---------------------------------------------------------------------------
// Fallback (tiny ws): fused per-step VALU kernel (round-1 proven). Slow.
// ---------------------------------------------------------------------------
__global__ __launch_bounds__(256) void lstm_step_fb(
    const float* __restrict__ xt, const float* __restrict__ Wx,
    const float* __restrict__ Wh, const float* __restrict__ bias,
    const float* __restrict__ h_prev, long long hstride,
    float* __restrict__ cbuf, float* __restrict__ h_out, int first) {
  __shared__ float hS[32][128];
  __shared__ float wT[32][132];
  __shared__ float pre[32][34];
  const int tid = threadIdx.x;
  const int colblk = blockIdx.x & 127;
  const int nh = blockIdx.x >> 7;
  const int j0 = colblk << 3;
  const int n0 = nh << 5;
  const int ng = tid >> 4, cg2 = tid & 15;
  const int na = ng << 1, ca = cg2 << 1;

  float acc[2][2] = {{0.f, 0.f}, {0.f, 0.f}};

#pragma unroll
  for (int pr = 0; pr < 2; ++pr) {
    const float* src = (pr == 0) ? h_prev : xt;
    long long sstr = (pr == 0) ? hstride : (long long)T_ * D_;
    const float* W = (pr == 0) ? Wh : Wx;
    for (int k0 = 0; k0 < 1024; k0 += 128) {
      __syncthreads();
#pragma unroll
      for (int p = 0; p < 4; ++p) {
        int idx = tid + (p << 8);
        int r = idx >> 5, c4 = (idx & 31) << 2;
        *reinterpret_cast<float4*>(&hS[r][c4]) =
            *reinterpret_cast<const float4*>(src + (size_t)(n0 + r) * sstr + k0 + c4);
      }
#pragma unroll
      for (int p = 0; p < 4; ++p) {
        int idx = tid + (p << 8);
        int k = idx >> 3, sub = idx & 7;
        int g = sub >> 1, hf = (sub & 1) << 2;
        float4 v = *reinterpret_cast<const float4*>(
            W + (size_t)(k0 + k) * FH + g * H_ + j0 + hf);
        int cb = (g << 3) + hf;
        wT[cb][k] = v.x; wT[cb + 1][k] = v.y; wT[cb + 2][k] = v.z; wT[cb + 3][k] = v.w;
      }
      __syncthreads();
#pragma unroll
      for (int kk = 0; kk < 128; kk += 4) {
        float4 h0v = *reinterpret_cast<const float4*>(&hS[na][kk]);
        float4 h1v = *reinterpret_cast<const float4*>(&hS[na + 1][kk]);
        float4 w0 = *reinterpret_cast<const float4*>(&wT[ca][kk]);
        float4 w1 = *reinterpret_cast<const float4*>(&wT[ca + 1][kk]);
        acc[0][0] = fmaf(h0v.x, w0.x, acc[0][0]); acc[0][0] = fmaf(h0v.y, w0.y, acc[0][0]);
        acc[0][0] = fmaf(h0v.z, w0.z, acc[0][0]); acc[0][0] = fmaf(h0v.w, w0.w, acc[0][0]);
        acc[0][1] = fmaf(h0v.x, w1.x, acc[0][1]); acc[0][1] = fmaf(h0v.y, w1.y, acc[0][1]);
        acc[0][1] = fmaf(h0v.z, w1.z, acc[0][1]); acc[0][1] = fmaf(h0v.w, w1.w, acc[0][1]);
        acc[1][0] = fmaf(h1v.x, w0.x, acc[1][0]); acc[1][0] = fmaf(h1v.y, w0.y, acc[1][0]);
        acc[1][0] = fmaf(h1v.z, w0.z, acc[1][0]); acc[1][0] = fmaf(h1v.w, w0.w, acc[1][0]);
        acc[1][1] = fmaf(h1v.x, w1.x, acc[1][1]); acc[1][1] = fmaf(h1v.y, w1.y, acc[1][1]);
        acc[1][1] = fmaf(h1v.z, w1.z, acc[1][1]); acc[1][1] = fmaf(h1v.w, w1.w, acc[1][1]);
      }
    }
  }

  pre[na][ca] = acc[0][0];
  pre[na][ca + 1] = acc[0][1];
  pre[na + 1][ca] = acc[1][0];
  pre[na + 1][ca + 1] = acc[1][1];
  __syncthreads();

  const int nl = tid >> 3, jl = tid & 7;
  const int n = n0 + nl;
  const int jg = j0 + jl;
  float ai = pre[nl][jl] + bias[jg];
  float af = pre[nl][8 + jl] + bias[H_ + jg];
  float ao = pre[nl][16 + jl] + bias[2 * H_ + jg];
  float ag = pre[nl][24 + jl] + bias[3 * H_ + jg];
  float cp = first ? 0.0f : cbuf[n * H_ + jg];
  float iv = 1.f / (1.f + __expf(-ai));
  float fv = 1.f / (1.f + __expf(-af));
  float ov = 1.f / (1.f + __expf(-ao));
  float gv = tanhf(ag);
  float cn = fmaf(fv, cp, iv * gv);
  cbuf[n * H_ + jg] = cn;
  h_out[(size_t)n * ((size_t)T_ * H_) + jg] = ov * tanhf(cn);
}

// ---------------------------------------------------------------------------
extern "C" void kernel_launch(void* const* d_in, const int* in_sizes, int n_in,
                              void* d_out, int out_size, void* d_ws, size_t ws_size,
                              hipStream_t stream) {
  (void)in_sizes; (void)n_in; (void)out_size;
  const float* x  = (const float*)d_in[0];
  const float* h0 = (const float*)d_in[1];
  const float* Wx = (const float*)d_in[2];
  const float* Wh = (const float*)d_in[3];
  const float* b  = (const float*)d_in[4];
  float* out = (float*)d_out;

  const size_t MB = 1u << 20;
  char* p = (char*)d_ws;

  if (ws_size >= 300 * MB) {
    unsigned* bar = (unsigned*)p;               // flags[256] + rel @ +384
    ushort* Whh = (ushort*)(p + 1 * MB);
    ushort* Whl = (ushort*)(p + 9 * MB);
    ushort* Wxh = (ushort*)(p + 17 * MB);
    ushort* Wxl = (ushort*)(p + 25 * MB);
    uint32_t* hseq = (uint32_t*)(p + 33 * MB);  // 513 * 256 KB = 128.25 MB
    ushort* xh = (ushort*)(p + 168 * MB);       // 64 MB
    ushort* xl = (ushort*)(p + 232 * MB);       // 64 MB (ends at 296 MB)

    pack_w_k<<<dim3(2048), dim3(256), 0, stream>>>(Wh, Whh, Whl);
    pack_w_k<<<dim3(2048), dim3(256), 0, stream>>>(Wx, Wxh, Wxl);
    // x: 8,388,608 float4 -> 32768 blocks (zeroes barrier words)
    split_f32_k<<<dim3(32768), dim3(256), 0, stream>>>(x, xh, xl, bar);
    // h0 -> packed u32 into hseq[0]
    conv_h0pk_k<<<dim3(64), dim3(256), 0, stream>>>(h0, hseq);

    const unsigned SH = 65536 + 128 * 17 * 4 + 8 * 64 * 16 * 4;  // 107008 B
    hipFuncSetAttribute((const void*)lstm_persist_mfma,
                        hipFuncAttributeMaxDynamicSharedMemorySize, (int)SH);
    lstm_persist_mfma<<<dim3(256), dim3(512), SH, stream>>>(
        Whh, Whl, Wxh, Wxl, xh, xl, b, hseq, out, bar);
  } else {
    float* cbuf = (float*)p;  // 256 KB
    for (int t = 0; t < T_; ++t) {
      const float* hp = (t == 0) ? h0 : out + (size_t)(t - 1) * H_;
      long long hstr = (t == 0) ? (long long)H_ : (long long)T_ * H_;
      lstm_step_fb<<<dim3(256), dim3(256), 0, stream>>>(
          x + (size_t)t * D_, Wx, Wh, b, hp, hstr, cbuf,
          out + (size_t)t * H_, t == 0);
    }
  }
}